// Round 2
// baseline (10401.347 us; speedup 1.0000x reference)
//
#include <hip/hip_runtime.h>
#include <hip/hip_bf16.h>
#include <math.h>

// ---------------------------------------------------------------------------
// Morpher forward, fp32 baseline (workspace-lean: ~191 MB).
// Shapes: B=8 T=1024 (BT=8192), N=4, K=3, S=7, DH=128, D=896, ND=3584,
// IO=1024, RANK=64, HIDDEN=3584.
// Phase tables (device-side, phase read from d_in[18]):
//   slot[k]  = {0, 1+(ph&1), 3+(ph&3)}
//   PERM[ph][k][n]: k==0 -> n ; k==1 -> (n+2*(ph&1))&3 ; k==2 -> (n+(ph&3))&3
// ---------------------------------------------------------------------------

#define BT   8192
#define DH   128
#define DD   896
#define ND   3584
#define IO   1024
#define RK   64
#define HID  3584

// ---------------------------------------------------------------------------
// Generic fp32 tiled GEMM.
//  C(MxN) = A(MxKd, row-major) @ B  [+ epilogue]
//  BKN=false: B is (N x Kd) row-major  (C = A @ B^T)
//  BKN=true : B is (Kd x N) row-major  (C = A @ B)
//  EPI 0: C = acc
//  EPI 1: C = gelu(acc + bias[col])             (exact erf gelu)
//  EPI 2: C = C + acc + bias[col]               (residual in-place)
//  EPI 4: replicate acc into z: for n in 0..3  C[r*3584 + n*896 + col] = acc
//  EPI 5: C += sp[0] * acc                      (in-place axpy)
// ---------------------------------------------------------------------------
template<int BM, int BN, int BK, int TM, int TN, bool BKN, int EPI>
__device__ __forceinline__ void gemm_tile(const float* __restrict__ A,
                                          const float* __restrict__ B,
                                          float* __restrict__ C,
                                          int N, int Kd,
                                          const float* __restrict__ bias,
                                          const float* __restrict__ sp)
{
    constexpr int THREADS = (BM / TM) * (BN / TN);
    constexpr int LDA = BM + 4;
    constexpr int LDB = BN + 4;
    __shared__ float As[BK][LDA];
    __shared__ float Bs[BK][LDB];

    const int tid = threadIdx.x;
    constexpr int NX = BN / TN;
    const int tx = tid % NX;
    const int ty = tid / NX;
    const int row0 = blockIdx.y * BM;
    const int col0 = blockIdx.x * BN;

    float acc[TM][TN];
#pragma unroll
    for (int i = 0; i < TM; ++i)
#pragma unroll
        for (int j = 0; j < TN; ++j) acc[i][j] = 0.f;

    for (int k0 = 0; k0 < Kd; k0 += BK) {
        constexpr int AF4 = BM * BK / 4;
        for (int f = tid; f < AF4; f += THREADS) {
            int r  = f / (BK / 4);
            int c4 = (f % (BK / 4)) * 4;
            float4 v = *(const float4*)(A + (size_t)(row0 + r) * Kd + k0 + c4);
            As[c4 + 0][r] = v.x; As[c4 + 1][r] = v.y;
            As[c4 + 2][r] = v.z; As[c4 + 3][r] = v.w;
        }
        if (BKN) {
            constexpr int BF4 = BK * BN / 4;
            for (int f = tid; f < BF4; f += THREADS) {
                int r  = f / (BN / 4);
                int c4 = (f % (BN / 4)) * 4;
                *(float4*)&Bs[r][c4] =
                    *(const float4*)(B + (size_t)(k0 + r) * N + col0 + c4);
            }
        } else {
            constexpr int BF4 = BN * BK / 4;
            for (int f = tid; f < BF4; f += THREADS) {
                int r  = f / (BK / 4);
                int c4 = (f % (BK / 4)) * 4;
                float4 v = *(const float4*)(B + (size_t)(col0 + r) * Kd + k0 + c4);
                Bs[c4 + 0][r] = v.x; Bs[c4 + 1][r] = v.y;
                Bs[c4 + 2][r] = v.z; Bs[c4 + 3][r] = v.w;
            }
        }
        __syncthreads();

#pragma unroll
        for (int kk = 0; kk < BK; ++kk) {
            float a[TM], b[TN];
#pragma unroll
            for (int i = 0; i < TM; i += 4)
                *(float4*)&a[i] = *(const float4*)&As[kk][ty * TM + i];
#pragma unroll
            for (int j = 0; j < TN; j += 4)
                *(float4*)&b[j] = *(const float4*)&Bs[kk][tx * TN + j];
#pragma unroll
            for (int i = 0; i < TM; ++i)
#pragma unroll
                for (int j = 0; j < TN; ++j)
                    acc[i][j] = fmaf(a[i], b[j], acc[i][j]);
        }
        __syncthreads();
    }

    const int crow = row0 + ty * TM;
    const int ccol = col0 + tx * TN;
    if (EPI == 0) {
#pragma unroll
        for (int i = 0; i < TM; ++i) {
            float* cp = C + (size_t)(crow + i) * N + ccol;
#pragma unroll
            for (int j = 0; j < TN; ++j) cp[j] = acc[i][j];
        }
    } else if (EPI == 1) {
#pragma unroll
        for (int i = 0; i < TM; ++i) {
            float* cp = C + (size_t)(crow + i) * N + ccol;
#pragma unroll
            for (int j = 0; j < TN; ++j) {
                float v = acc[i][j] + bias[ccol + j];
                cp[j] = 0.5f * v * (1.0f + erff(v * 0.70710678118654752f));
            }
        }
    } else if (EPI == 2) {
#pragma unroll
        for (int i = 0; i < TM; ++i) {
            float* cp = C + (size_t)(crow + i) * N + ccol;
#pragma unroll
            for (int j = 0; j < TN; ++j)
                cp[j] = cp[j] + acc[i][j] + bias[ccol + j];
        }
    } else if (EPI == 4) {
#pragma unroll
        for (int i = 0; i < TM; ++i) {
            float* cp = C + (size_t)(crow + i) * ND + ccol;
#pragma unroll
            for (int n = 0; n < 4; ++n)
#pragma unroll
                for (int j = 0; j < TN; ++j) cp[n * DD + j] = acc[i][j];
        }
    } else { // EPI == 5
        float beta = sp[0];
#pragma unroll
        for (int i = 0; i < TM; ++i) {
            float* cp = C + (size_t)(crow + i) * N + ccol;
#pragma unroll
            for (int j = 0; j < TN; ++j) cp[j] += beta * acc[i][j];
        }
    }
}

template<int BM, int BN, int BK, int TM, int TN, bool BKN, int EPI>
__global__ __launch_bounds__(256) void gemm_kernel(const float* __restrict__ A,
                                                   const float* __restrict__ B,
                                                   float* __restrict__ C,
                                                   int N, int Kd,
                                                   const float* __restrict__ bias,
                                                   const float* __restrict__ sp)
{
    gemm_tile<BM, BN, BK, TM, TN, BKN, EPI>(A, B, C, N, Kd, bias, sp);
}

// ---------------------------------------------------------------------------
// Per-head QKV GEMM for a group of 24 heads (2 batches):
//   zb_local = blockIdx.z, global head zb = go + zb_local.
//   C(1024x384) = Xh(1024x128) @ Wqkv[k, PERM[ph][k][n]] (128x384)
// grid = (3, 8, 24)
// ---------------------------------------------------------------------------
__global__ __launch_bounds__(256) void qkv_kernel(const float* __restrict__ xh,
                                                  const float* __restrict__ Wqkv,
                                                  float* __restrict__ qkvb,
                                                  const int* __restrict__ phase_p,
                                                  int go)
{
    const int ph  = phase_p[0] & 3;
    const int zbl = blockIdx.z;
    const int hh  = (go + zbl) % 12;
    const int n   = hh / 3;
    const int k   = hh % 3;
    const int m   = (k == 0) ? n
                  : (k == 1) ? ((n + 2 * (ph & 1)) & 3)
                             : ((n + (ph & 3)) & 3);
    const float* A = xh   + (size_t)zbl * (1024 * 128);
    const float* B = Wqkv + (size_t)(k * 4 + m) * (128 * 384);
    float*       C = qkvb + (size_t)zbl * (1024 * 384);
    gemm_tile<128, 128, 16, 8, 8, true, 0>(A, B, C, 384, 128, nullptr, nullptr);
}

// ---------------------------------------------------------------------------
// Attention-input LayerNorm for a group of 2 batches: one wave per row of 128.
// Reads z0 slot, writes xh in local (b_local,N,K,T,128) head-major layout.
// grid = 6144 blocks (24576 rows / 4 waves per block)
// ---------------------------------------------------------------------------
__global__ __launch_bounds__(256) void ln_attn_kernel(const float* __restrict__ z,
                                                      float* __restrict__ xh,
                                                      const float* __restrict__ scale,
                                                      const float* __restrict__ bias,
                                                      const int* __restrict__ phase_p,
                                                      int bt0)
{
    const int ph   = phase_p[0] & 3;
    const int lane = threadIdx.x & 63;
    const int row  = blockIdx.x * 4 + (threadIdx.x >> 6);   // local bt*12 + n*3 + k
    const int k    = row % 3;
    const int n    = (row / 3) & 3;
    const int btl  = row / 12;                               // [0, 2048)
    const int slot = (k == 0) ? 0 : (k == 1 ? 1 + (ph & 1) : 3 + (ph & 3));
    const int bt   = bt0 + btl;

    const float* src = z + (size_t)bt * ND + n * DD + slot * DH + lane * 2;
    float2 v = *(const float2*)src;
    float s = v.x + v.y;
    float q = v.x * v.x + v.y * v.y;
#pragma unroll
    for (int m = 32; m; m >>= 1) { s += __shfl_xor(s, m); q += __shfl_xor(q, m); }
    float mu  = s * (1.0f / 128.0f);
    float var = q * (1.0f / 128.0f) - mu * mu;
    float r   = rsqrtf(var + 1e-5f);

    float2 sc2 = *(const float2*)(scale + lane * 2);
    float2 bi2 = *(const float2*)(bias + lane * 2);
    float2 o;
    o.x = (v.x - mu) * r * sc2.x + bi2.x;
    o.y = (v.y - mu) * r * sc2.y + bi2.y;
    const int bl = btl >> 10, t = btl & 1023;
    *(float2*)(xh + (size_t)((bl * 12 + n * 3 + k) * 1024 + t) * DH + lane * 2) = o;
}

// ---------------------------------------------------------------------------
// Row LayerNorm (W = 896 / 3584), one block per row. Safe in-place (each
// thread caches its values in registers before any write).
// ---------------------------------------------------------------------------
template<int W>
__global__ __launch_bounds__(256) void ln_row_kernel(const float* __restrict__ in,
                                                     float* __restrict__ outp,
                                                     const float* __restrict__ scale,
                                                     const float* __restrict__ bias)
{
    constexpr int NIT = (W + 255) / 256;
    const int row = blockIdx.x;
    const int tid = threadIdx.x;
    const float* rp = in + (size_t)row * W;

    float v[NIT];
    float s = 0.f, q = 0.f;
#pragma unroll
    for (int i = 0; i < NIT; ++i) {
        int idx = tid + i * 256;
        if (idx < W) { float t = rp[idx]; v[i] = t; s += t; q += t * t; }
        else v[i] = 0.f;
    }
#pragma unroll
    for (int m = 32; m; m >>= 1) { s += __shfl_xor(s, m); q += __shfl_xor(q, m); }
    __shared__ float ss[4], sq[4];
    if ((tid & 63) == 0) { ss[tid >> 6] = s; sq[tid >> 6] = q; }
    __syncthreads();
    s = ss[0] + ss[1] + ss[2] + ss[3];
    q = sq[0] + sq[1] + sq[2] + sq[3];
    float mu  = s * (1.0f / W);
    float var = q * (1.0f / W) - mu * mu;
    float r   = rsqrtf(var + 1e-5f);

    float* op = outp + (size_t)row * W;
#pragma unroll
    for (int i = 0; i < NIT; ++i) {
        int idx = tid + i * 256;
        if (idx < W) op[idx] = (v[i] - mu) * r * scale[idx] + bias[idx];
    }
}

// ---------------------------------------------------------------------------
// Flash attention (fp32): grid (16 q-tiles, 24 heads), 256 threads.
// Q tile 64 rows; KV tiles 32 rows; K and V share one LDS buffer.
// Online softmax; output added directly into z at the head's slot (z1).
// LDS: Qs 34816 + KV 18432 + PsT 8704 = 61952 B (< 64 KB).
// ---------------------------------------------------------------------------
__global__ __launch_bounds__(256) void flash_attn_kernel(const float* __restrict__ qkvb,
                                                         float* __restrict__ z,
                                                         const int* __restrict__ phase_p,
                                                         int go)
{
    __shared__ float Qs[128][68];   // [d][r]
    __shared__ float KV[4608];      // K: [d*36+c] ; V: [kv*132+c]
    __shared__ float PsT[32][68];   // [c][r]

    const int ph  = phase_p[0] & 3;
    const int zbl = blockIdx.y;
    const int zb  = go + zbl;
    const int b   = zb / 12;
    const int hh  = zb % 12;
    const int n   = hh / 3;
    const int ks  = hh % 3;
    const int slot = (ks == 0) ? 0 : (ks == 1 ? 1 + (ph & 1) : 3 + (ph & 3));
    const int q0  = blockIdx.x * 64;

    const float* Qp = qkvb + (size_t)zbl * (1024 * 384);
    const float* Kp = Qp + 128;
    const float* Vp = Qp + 256;

    const int tid = threadIdx.x;
    const int tx  = tid & 15;
    const int ty  = tid >> 4;

    for (int f = tid; f < 2048; f += 256) {
        int r = f >> 5, c4 = (f & 31) << 2;
        float4 v = *(const float4*)(Qp + (size_t)(q0 + r) * 384 + c4);
        Qs[c4 + 0][r] = v.x; Qs[c4 + 1][r] = v.y;
        Qs[c4 + 2][r] = v.z; Qs[c4 + 3][r] = v.w;
    }

    float m_i[4], l_i[4], O[4][8];
#pragma unroll
    for (int i = 0; i < 4; ++i) {
        m_i[i] = -1e30f; l_i[i] = 0.f;
#pragma unroll
        for (int j = 0; j < 8; ++j) O[i][j] = 0.f;
    }
    const float sc = 0.08838834764831845f;  // 1/sqrt(128)

    const int jend = q0 + 32;
    for (int j0 = 0; j0 <= jend; j0 += 32) {
        for (int f = tid; f < 1024; f += 256) {
            int r = f >> 5, c4 = (f & 31) << 2;
            float4 v = *(const float4*)(Kp + (size_t)(j0 + r) * 384 + c4);
            KV[(c4 + 0) * 36 + r] = v.x; KV[(c4 + 1) * 36 + r] = v.y;
            KV[(c4 + 2) * 36 + r] = v.z; KV[(c4 + 3) * 36 + r] = v.w;
        }
        __syncthreads();

        float S[4][2] = {{0.f, 0.f}, {0.f, 0.f}, {0.f, 0.f}, {0.f, 0.f}};
#pragma unroll 4
        for (int d = 0; d < 128; ++d) {
            float a[4];
            *(float4*)a = *(const float4*)&Qs[d][ty * 4];
            float2 bb = *(const float2*)&KV[d * 36 + tx * 2];
#pragma unroll
            for (int i = 0; i < 4; ++i) {
                S[i][0] = fmaf(a[i], bb.x, S[i][0]);
                S[i][1] = fmaf(a[i], bb.y, S[i][1]);
            }
        }

        const bool need_mask = (j0 + 31 > q0);
        float alpha[4];
#pragma unroll
        for (int i = 0; i < 4; ++i) {
            int tq = q0 + ty * 4 + i;
            float s0 = S[i][0] * sc, s1 = S[i][1] * sc;
            if (need_mask) {
                if (j0 + tx * 2 + 0 > tq) s0 = -1e30f;
                if (j0 + tx * 2 + 1 > tq) s1 = -1e30f;
            }
            float mx = fmaxf(s0, s1);
#pragma unroll
            for (int msk = 8; msk; msk >>= 1) mx = fmaxf(mx, __shfl_xor(mx, msk, 16));
            float mnew = fmaxf(m_i[i], mx);
            float al   = expf(m_i[i] - mnew);
            s0 = expf(s0 - mnew); s1 = expf(s1 - mnew);
            float rs = s0 + s1;
#pragma unroll
            for (int msk = 8; msk; msk >>= 1) rs += __shfl_xor(rs, msk, 16);
            l_i[i]  = l_i[i] * al + rs;
            m_i[i]  = mnew;
            alpha[i] = al;
            S[i][0] = s0; S[i][1] = s1;
        }
#pragma unroll
        for (int j = 0; j < 2; ++j) {
            float4 col;
            col.x = S[0][j]; col.y = S[1][j]; col.z = S[2][j]; col.w = S[3][j];
            *(float4*)&PsT[tx * 2 + j][ty * 4] = col;
        }
#pragma unroll
        for (int i = 0; i < 4; ++i)
#pragma unroll
            for (int j = 0; j < 8; ++j) O[i][j] *= alpha[i];
        __syncthreads();

        for (int f = tid; f < 1024; f += 256) {
            int r = f >> 5, c4 = (f & 31) << 2;
            float4 v = *(const float4*)(Vp + (size_t)(j0 + r) * 384 + c4);
            *(float4*)&KV[r * 132 + c4] = v;
        }
        __syncthreads();

#pragma unroll 4
        for (int kv = 0; kv < 32; ++kv) {
            float p[4];
            *(float4*)p = *(const float4*)&PsT[kv][ty * 4];
            float vv[8];
            *(float4*)&vv[0] = *(const float4*)&KV[kv * 132 + tx * 8];
            *(float4*)&vv[4] = *(const float4*)&KV[kv * 132 + tx * 8 + 4];
#pragma unroll
            for (int i = 0; i < 4; ++i)
#pragma unroll
                for (int j = 0; j < 8; ++j) O[i][j] = fmaf(p[i], vv[j], O[i][j]);
        }
        __syncthreads();
    }

#pragma unroll
    for (int i = 0; i < 4; ++i) {
        int t = q0 + ty * 4 + i;
        float inv = 1.0f / l_i[i];
        float* dst = z + (size_t)(b * 1024 + t) * ND + n * DD + slot * DH + tx * 8;
#pragma unroll
        for (int j = 0; j < 8; ++j) dst[j] += O[i][j] * inv;
    }
}

// ---------------------------------------------------------------------------
// Launcher. Workspace: z (29,360,128 f) + R (18,350,080 f) = 190.8 MB.
// ---------------------------------------------------------------------------
extern "C" void kernel_launch(void* const* d_in, const int* in_sizes, int n_in,
                              void* d_out, int out_size, void* d_ws, size_t ws_size,
                              hipStream_t stream)
{
    const float* x          = (const float*)d_in[0];
    const float* enc_base_w = (const float*)d_in[1];
    const float* enc_A_w    = (const float*)d_in[2];
    const float* enc_B      = (const float*)d_in[3];
    const float* enc_beta   = (const float*)d_in[4];
    const float* Wqkv       = (const float*)d_in[5];
    const float* ln_attn_s  = (const float*)d_in[6];
    const float* ln_attn_b  = (const float*)d_in[7];
    const float* ln_mix_s   = (const float*)d_in[8];
    const float* ln_mix_b   = (const float*)d_in[9];
    const float* w1         = (const float*)d_in[10];
    const float* b1         = (const float*)d_in[11];
    const float* w2         = (const float*)d_in[12];
    const float* b2         = (const float*)d_in[13];
    const float* dec_ln_s   = (const float*)d_in[14];
    const float* dec_ln_b   = (const float*)d_in[15];
    const float* dec_down   = (const float*)d_in[16];
    const float* dec_up     = (const float*)d_in[17];
    const int*   phase_p    = (const int*)d_in[18];
    float* out = (float*)d_out;

    float* ws = (float*)d_ws;
    float* z  = ws;                                  // 8192*3584 (persistent)
    float* R  = ws + (size_t)BT * ND;                // reusable region (18.35M f)
    // enc phase
    float* hbuf = R;                                 // 8192*64
    // attn phase (per group of 24 heads)
    float* xh   = R;                                 // 24*1024*128 = 3,145,728
    float* qkvb = R + (size_t)24 * 1024 * 128;       // 24*1024*384 = 9,437,184
    // mixer phase (per chunk of 4096 rows)
    float* hm   = R;                                 // 4096*896  = 3,670,016
    float* gbuf = R + (size_t)4096 * DD;             // 4096*3584 = 14,680,064
    // dec phase
    float* t1   = R;                                 // 8192*64

    // G1: h = x @ enc_A_w^T            (8192 x 64, K=1024)
    gemm_kernel<64, 64, 16, 4, 4, false, 0>
        <<<dim3(1, 128), 256, 0, stream>>>(x, enc_A_w, hbuf, RK, IO, nullptr, nullptr);
    // G2: base replicated into z       (8192 x 896 -> 4 copies, K=1024)
    gemm_kernel<128, 128, 16, 8, 8, false, 4>
        <<<dim3(7, 64), 256, 0, stream>>>(x, enc_base_w, z, DD, IO, nullptr, nullptr);
    // G3: z += beta * (h @ enc_B)      (8192 x 3584, K=64), in-place
    gemm_kernel<128, 128, 16, 8, 8, true, 5>
        <<<dim3(28, 64), 256, 0, stream>>>(hbuf, enc_B, z, ND, RK, nullptr, enc_beta);

    // Attention in 4 groups of 24 heads (2 batches each)
    for (int g = 0; g < 4; ++g) {
        ln_attn_kernel<<<dim3(6144), 256, 0, stream>>>(z, xh, ln_attn_s, ln_attn_b,
                                                       phase_p, g * 2048);
        qkv_kernel<<<dim3(3, 8, 24), 256, 0, stream>>>(xh, Wqkv, qkvb, phase_p, g * 24);
        flash_attn_kernel<<<dim3(16, 24), 256, 0, stream>>>(qkvb, z, phase_p, g * 24);
    }

    // Mixer MLP in 8 row-chunks of 4096 (of 32768 rows x 896)
    for (int c = 0; c < 8; ++c) {
        const size_t ro = (size_t)c * 4096;
        ln_row_kernel<896><<<dim3(4096), 256, 0, stream>>>(z + ro * DD, hm,
                                                           ln_mix_s, ln_mix_b);
        gemm_kernel<128, 128, 16, 8, 8, false, 1>
            <<<dim3(28, 32), 256, 0, stream>>>(hm, w1, gbuf, HID, DD, b1, nullptr);
        gemm_kernel<128, 128, 16, 8, 8, false, 2>
            <<<dim3(7, 32), 256, 0, stream>>>(gbuf, w2, z + ro * DD, DD, HID, b2, nullptr);
    }

    // Decoder: LN in place, then low-rank down/up
    ln_row_kernel<3584><<<dim3(8192), 256, 0, stream>>>(z, z, dec_ln_s, dec_ln_b);
    gemm_kernel<64, 64, 16, 4, 4, false, 0>
        <<<dim3(1, 128), 256, 0, stream>>>(z, dec_down, t1, RK, ND, nullptr, nullptr);
    gemm_kernel<128, 128, 16, 8, 8, false, 0>
        <<<dim3(8, 64), 256, 0, stream>>>(t1, dec_up, out, IO, RK, nullptr, nullptr);
}

// Round 3
// 3689.279 us; speedup vs baseline: 2.8193x; 2.8193x over previous
//
#include <hip/hip_runtime.h>
#include <hip/hip_bf16.h>
#include <math.h>

// ---------------------------------------------------------------------------
// Morpher forward. Mixer MLP on bf16 MFMA (m97-style), rest fp32.
// Shapes: B=8 T=1024 (BT=8192), N=4, K=3, S=7, DH=128, D=896, ND=3584,
// IO=1024, RANK=64, HIDDEN=3584.
// Phase tables (device-side, phase read from d_in[18]):
//   slot[k]  = {0, 1+(ph&1), 3+(ph&3)}
//   PERM[ph][k][n]: k==0 -> n ; k==1 -> (n+2*(ph&1))&3 ; k==2 -> (n+(ph&3))&3
// ---------------------------------------------------------------------------

#define BT   8192
#define DH   128
#define DD   896
#define ND   3584
#define IO   1024
#define RK   64
#define HID  3584

typedef __attribute__((ext_vector_type(8))) short short8;
typedef __attribute__((ext_vector_type(4))) float f32x4;

// ---------------------------------------------------------------------------
// fp32 tiled GEMM (unchanged, used for encoder/QKV/decoder).
//  EPI 0: C = acc
//  EPI 4: replicate acc into z row (4 copies at n*896)
//  EPI 5: C += sp[0] * acc
// ---------------------------------------------------------------------------
template<int BM, int BN, int BK, int TM, int TN, bool BKN, int EPI>
__device__ __forceinline__ void gemm_tile(const float* __restrict__ A,
                                          const float* __restrict__ B,
                                          float* __restrict__ C,
                                          int N, int Kd,
                                          const float* __restrict__ bias,
                                          const float* __restrict__ sp)
{
    constexpr int THREADS = (BM / TM) * (BN / TN);
    constexpr int LDA = BM + 4;
    constexpr int LDB = BN + 4;
    __shared__ float As[BK][LDA];
    __shared__ float Bs[BK][LDB];

    const int tid = threadIdx.x;
    constexpr int NX = BN / TN;
    const int tx = tid % NX;
    const int ty = tid / NX;
    const int row0 = blockIdx.y * BM;
    const int col0 = blockIdx.x * BN;

    float acc[TM][TN];
#pragma unroll
    for (int i = 0; i < TM; ++i)
#pragma unroll
        for (int j = 0; j < TN; ++j) acc[i][j] = 0.f;

    for (int k0 = 0; k0 < Kd; k0 += BK) {
        constexpr int AF4 = BM * BK / 4;
        for (int f = tid; f < AF4; f += THREADS) {
            int r  = f / (BK / 4);
            int c4 = (f % (BK / 4)) * 4;
            float4 v = *(const float4*)(A + (size_t)(row0 + r) * Kd + k0 + c4);
            As[c4 + 0][r] = v.x; As[c4 + 1][r] = v.y;
            As[c4 + 2][r] = v.z; As[c4 + 3][r] = v.w;
        }
        if (BKN) {
            constexpr int BF4 = BK * BN / 4;
            for (int f = tid; f < BF4; f += THREADS) {
                int r  = f / (BN / 4);
                int c4 = (f % (BN / 4)) * 4;
                *(float4*)&Bs[r][c4] =
                    *(const float4*)(B + (size_t)(k0 + r) * N + col0 + c4);
            }
        } else {
            constexpr int BF4 = BN * BK / 4;
            for (int f = tid; f < BF4; f += THREADS) {
                int r  = f / (BK / 4);
                int c4 = (f % (BK / 4)) * 4;
                float4 v = *(const float4*)(B + (size_t)(col0 + r) * Kd + k0 + c4);
                Bs[c4 + 0][r] = v.x; Bs[c4 + 1][r] = v.y;
                Bs[c4 + 2][r] = v.z; Bs[c4 + 3][r] = v.w;
            }
        }
        __syncthreads();

#pragma unroll
        for (int kk = 0; kk < BK; ++kk) {
            float a[TM], b[TN];
#pragma unroll
            for (int i = 0; i < TM; i += 4)
                *(float4*)&a[i] = *(const float4*)&As[kk][ty * TM + i];
#pragma unroll
            for (int j = 0; j < TN; j += 4)
                *(float4*)&b[j] = *(const float4*)&Bs[kk][tx * TN + j];
#pragma unroll
            for (int i = 0; i < TM; ++i)
#pragma unroll
                for (int j = 0; j < TN; ++j)
                    acc[i][j] = fmaf(a[i], b[j], acc[i][j]);
        }
        __syncthreads();
    }

    const int crow = row0 + ty * TM;
    const int ccol = col0 + tx * TN;
    if (EPI == 0) {
#pragma unroll
        for (int i = 0; i < TM; ++i) {
            float* cp = C + (size_t)(crow + i) * N + ccol;
#pragma unroll
            for (int j = 0; j < TN; ++j) cp[j] = acc[i][j];
        }
    } else if (EPI == 4) {
#pragma unroll
        for (int i = 0; i < TM; ++i) {
            float* cp = C + (size_t)(crow + i) * ND + ccol;
#pragma unroll
            for (int n = 0; n < 4; ++n)
#pragma unroll
                for (int j = 0; j < TN; ++j) cp[n * DD + j] = acc[i][j];
        }
    } else { // EPI == 5
        float beta = sp[0];
#pragma unroll
        for (int i = 0; i < TM; ++i) {
            float* cp = C + (size_t)(crow + i) * N + ccol;
#pragma unroll
            for (int j = 0; j < TN; ++j) cp[j] += beta * acc[i][j];
        }
    }
}

template<int BM, int BN, int BK, int TM, int TN, bool BKN, int EPI>
__global__ __launch_bounds__(256) void gemm_kernel(const float* __restrict__ A,
                                                   const float* __restrict__ B,
                                                   float* __restrict__ C,
                                                   int N, int Kd,
                                                   const float* __restrict__ bias,
                                                   const float* __restrict__ sp)
{
    gemm_tile<BM, BN, BK, TM, TN, BKN, EPI>(A, B, C, N, Kd, bias, sp);
}

// ---------------------------------------------------------------------------
// bf16 MFMA GEMM: C(MxN) = A(MxK bf16, row-major) @ B(NxK bf16, row-major)^T
// Block 128x128, 4 waves (2x2), each wave 64x64 via 4x4 mfma_f32_16x16x32_bf16.
// BK=64, global_load_lds width-16 staging, unpadded [row][k] LDS tiles.
//  EPI 1: Cb[row*N+col] = bf16(gelu(acc + bias[col]))
//  EPI 2: Cf[row*N+col] += acc + bias[col]
// Requires: M%128==0, N%128==0, Kd%64==0; A,B rows 16B-aligned.
// ---------------------------------------------------------------------------
template<int EPI>
__global__ __launch_bounds__(256) void gemm_bf16_kernel(
    const __hip_bfloat16* __restrict__ A,
    const __hip_bfloat16* __restrict__ B,
    float* __restrict__ Cf,
    __hip_bfloat16* __restrict__ Cb,
    int N, int Kd,
    const float* __restrict__ bias)
{
    __shared__ __hip_bfloat16 As[128 * 64];
    __shared__ __hip_bfloat16 Bs[128 * 64];

    const int tid  = threadIdx.x;
    const int wave = tid >> 6;
    const int lane = tid & 63;
    const int wm = wave >> 1, wn = wave & 1;
    const int row0 = blockIdx.y * 128;
    const int col0 = blockIdx.x * 128;
    const int lr = lane & 15;        // fragment m/n index
    const int lq = lane >> 4;        // k-quad / d-row group
    const int srow = lane >> 3;      // staging: row within 8-row group
    const int scol = (lane & 7) * 8; // staging: bf16 col offset (16 B)

    f32x4 acc[4][4];
#pragma unroll
    for (int i = 0; i < 4; ++i)
#pragma unroll
        for (int j = 0; j < 4; ++j) acc[i][j] = (f32x4){0.f, 0.f, 0.f, 0.f};

    for (int k0 = 0; k0 < Kd; k0 += 64) {
        // stage A tile rows [wave*32, wave*32+32), 8 rows per instruction
#pragma unroll
        for (int j = 0; j < 4; ++j) {
            const int rg = wave * 32 + j * 8;   // wave-uniform group base row
            __builtin_amdgcn_global_load_lds(
                (const __attribute__((address_space(1))) unsigned int*)
                    (A + (size_t)(row0 + rg + srow) * Kd + k0 + scol),
                (__attribute__((address_space(3))) unsigned int*)(As + rg * 64),
                16, 0, 0);
        }
#pragma unroll
        for (int j = 0; j < 4; ++j) {
            const int rg = wave * 32 + j * 8;
            __builtin_amdgcn_global_load_lds(
                (const __attribute__((address_space(1))) unsigned int*)
                    (B + (size_t)(col0 + rg + srow) * Kd + k0 + scol),
                (__attribute__((address_space(3))) unsigned int*)(Bs + rg * 64),
                16, 0, 0);
        }
        __syncthreads();

#pragma unroll
        for (int s = 0; s < 64; s += 32) {
            short8 af[4], bf[4];
#pragma unroll
            for (int mt = 0; mt < 4; ++mt)
                af[mt] = *(const short8*)&As[(wm * 64 + mt * 16 + lr) * 64 + s + lq * 8];
#pragma unroll
            for (int nt = 0; nt < 4; ++nt)
                bf[nt] = *(const short8*)&Bs[(wn * 64 + nt * 16 + lr) * 64 + s + lq * 8];
#pragma unroll
            for (int mt = 0; mt < 4; ++mt)
#pragma unroll
                for (int nt = 0; nt < 4; ++nt)
                    acc[mt][nt] = __builtin_amdgcn_mfma_f32_16x16x32_bf16(
                        af[mt], bf[nt], acc[mt][nt], 0, 0, 0);
        }
        __syncthreads();
    }

    // epilogue: D layout col=lane&15, row=(lane>>4)*4+reg
#pragma unroll
    for (int mt = 0; mt < 4; ++mt) {
#pragma unroll
        for (int nt = 0; nt < 4; ++nt) {
            const int col = col0 + wn * 64 + nt * 16 + lr;
            const float bcol = bias[col];
#pragma unroll
            for (int r = 0; r < 4; ++r) {
                const int row = row0 + wm * 64 + mt * 16 + lq * 4 + r;
                float v = acc[mt][nt][r] + bcol;
                if (EPI == 1) {
                    v = 0.5f * v * (1.0f + erff(v * 0.70710678118654752f));
                    Cb[(size_t)row * N + col] = __float2bfloat16(v);
                } else {
                    Cf[(size_t)row * N + col] += v;
                }
            }
        }
    }
}

// ---------------------------------------------------------------------------
// fp32 -> bf16 elementwise (n4 = n/4)
// ---------------------------------------------------------------------------
__global__ __launch_bounds__(256) void cvt_bf16_kernel(const float* __restrict__ src,
                                                       __hip_bfloat16* __restrict__ dst,
                                                       int n4)
{
    int i = blockIdx.x * 256 + threadIdx.x;
    if (i < n4) {
        float4 v = ((const float4*)src)[i];
        __hip_bfloat16* d = dst + (size_t)i * 4;
        d[0] = __float2bfloat16(v.x);
        d[1] = __float2bfloat16(v.y);
        d[2] = __float2bfloat16(v.z);
        d[3] = __float2bfloat16(v.w);
    }
}

// ---------------------------------------------------------------------------
// Per-head QKV GEMM for a group of 24 heads (2 batches). grid = (3, 8, 24)
// ---------------------------------------------------------------------------
__global__ __launch_bounds__(256) void qkv_kernel(const float* __restrict__ xh,
                                                  const float* __restrict__ Wqkv,
                                                  float* __restrict__ qkvb,
                                                  const int* __restrict__ phase_p,
                                                  int go)
{
    const int ph  = phase_p[0] & 3;
    const int zbl = blockIdx.z;
    const int hh  = (go + zbl) % 12;
    const int n   = hh / 3;
    const int k   = hh % 3;
    const int m   = (k == 0) ? n
                  : (k == 1) ? ((n + 2 * (ph & 1)) & 3)
                             : ((n + (ph & 3)) & 3);
    const float* A = xh   + (size_t)zbl * (1024 * 128);
    const float* B = Wqkv + (size_t)(k * 4 + m) * (128 * 384);
    float*       C = qkvb + (size_t)zbl * (1024 * 384);
    gemm_tile<128, 128, 16, 8, 8, true, 0>(A, B, C, 384, 128, nullptr, nullptr);
}

// ---------------------------------------------------------------------------
// Attention-input LayerNorm (group of 2 batches). grid = 6144
// ---------------------------------------------------------------------------
__global__ __launch_bounds__(256) void ln_attn_kernel(const float* __restrict__ z,
                                                      float* __restrict__ xh,
                                                      const float* __restrict__ scale,
                                                      const float* __restrict__ bias,
                                                      const int* __restrict__ phase_p,
                                                      int bt0)
{
    const int ph   = phase_p[0] & 3;
    const int lane = threadIdx.x & 63;
    const int row  = blockIdx.x * 4 + (threadIdx.x >> 6);
    const int k    = row % 3;
    const int n    = (row / 3) & 3;
    const int btl  = row / 12;
    const int slot = (k == 0) ? 0 : (k == 1 ? 1 + (ph & 1) : 3 + (ph & 3));
    const int bt   = bt0 + btl;

    const float* src = z + (size_t)bt * ND + n * DD + slot * DH + lane * 2;
    float2 v = *(const float2*)src;
    float s = v.x + v.y;
    float q = v.x * v.x + v.y * v.y;
#pragma unroll
    for (int m = 32; m; m >>= 1) { s += __shfl_xor(s, m); q += __shfl_xor(q, m); }
    float mu  = s * (1.0f / 128.0f);
    float var = q * (1.0f / 128.0f) - mu * mu;
    float r   = rsqrtf(var + 1e-5f);

    float2 sc2 = *(const float2*)(scale + lane * 2);
    float2 bi2 = *(const float2*)(bias + lane * 2);
    float2 o;
    o.x = (v.x - mu) * r * sc2.x + bi2.x;
    o.y = (v.y - mu) * r * sc2.y + bi2.y;
    const int bl = btl >> 10, t = btl & 1023;
    *(float2*)(xh + (size_t)((bl * 12 + n * 3 + k) * 1024 + t) * DH + lane * 2) = o;
}

// ---------------------------------------------------------------------------
// Row LayerNorm fp32 out (W=3584 decoder), safe in-place.
// ---------------------------------------------------------------------------
template<int W>
__global__ __launch_bounds__(256) void ln_row_kernel(const float* __restrict__ in,
                                                     float* __restrict__ outp,
                                                     const float* __restrict__ scale,
                                                     const float* __restrict__ bias)
{
    constexpr int NIT = (W + 255) / 256;
    const int row = blockIdx.x;
    const int tid = threadIdx.x;
    const float* rp = in + (size_t)row * W;

    float v[NIT];
    float s = 0.f, q = 0.f;
#pragma unroll
    for (int i = 0; i < NIT; ++i) {
        int idx = tid + i * 256;
        if (idx < W) { float t = rp[idx]; v[i] = t; s += t; q += t * t; }
        else v[i] = 0.f;
    }
#pragma unroll
    for (int m = 32; m; m >>= 1) { s += __shfl_xor(s, m); q += __shfl_xor(q, m); }
    __shared__ float ss[4], sq[4];
    if ((tid & 63) == 0) { ss[tid >> 6] = s; sq[tid >> 6] = q; }
    __syncthreads();
    s = ss[0] + ss[1] + ss[2] + ss[3];
    q = sq[0] + sq[1] + sq[2] + sq[3];
    float mu  = s * (1.0f / W);
    float var = q * (1.0f / W) - mu * mu;
    float r   = rsqrtf(var + 1e-5f);

    float* op = outp + (size_t)row * W;
#pragma unroll
    for (int i = 0; i < NIT; ++i) {
        int idx = tid + i * 256;
        if (idx < W) op[idx] = (v[i] - mu) * r * scale[idx] + bias[idx];
    }
}

// ---------------------------------------------------------------------------
// Row LayerNorm, W=896, bf16 output (mixer input).
// ---------------------------------------------------------------------------
__global__ __launch_bounds__(256) void ln_row_bf16_kernel(const float* __restrict__ in,
                                                          __hip_bfloat16* __restrict__ outp,
                                                          const float* __restrict__ scale,
                                                          const float* __restrict__ bias)
{
    constexpr int W = 896, NIT = 4;
    const int row = blockIdx.x;
    const int tid = threadIdx.x;
    const float* rp = in + (size_t)row * W;

    float v[NIT];
    float s = 0.f, q = 0.f;
#pragma unroll
    for (int i = 0; i < NIT; ++i) {
        int idx = tid + i * 256;
        if (idx < W) { float t = rp[idx]; v[i] = t; s += t; q += t * t; }
        else v[i] = 0.f;
    }
#pragma unroll
    for (int m = 32; m; m >>= 1) { s += __shfl_xor(s, m); q += __shfl_xor(q, m); }
    __shared__ float ss[4], sq[4];
    if ((tid & 63) == 0) { ss[tid >> 6] = s; sq[tid >> 6] = q; }
    __syncthreads();
    s = ss[0] + ss[1] + ss[2] + ss[3];
    q = sq[0] + sq[1] + sq[2] + sq[3];
    float mu  = s * (1.0f / W);
    float var = q * (1.0f / W) - mu * mu;
    float r   = rsqrtf(var + 1e-5f);

    __hip_bfloat16* op = outp + (size_t)row * W;
#pragma unroll
    for (int i = 0; i < NIT; ++i) {
        int idx = tid + i * 256;
        if (idx < W)
            op[idx] = __float2bfloat16((v[i] - mu) * r * scale[idx] + bias[idx]);
    }
}

// ---------------------------------------------------------------------------
// Flash attention (fp32): grid (16 q-tiles, 24 heads), 256 threads.
// ---------------------------------------------------------------------------
__global__ __launch_bounds__(256) void flash_attn_kernel(const float* __restrict__ qkvb,
                                                         float* __restrict__ z,
                                                         const int* __restrict__ phase_p,
                                                         int go)
{
    __shared__ float Qs[128][68];
    __shared__ float KV[4608];
    __shared__ float PsT[32][68];

    const int ph  = phase_p[0] & 3;
    const int zbl = blockIdx.y;
    const int zb  = go + zbl;
    const int b   = zb / 12;
    const int hh  = zb % 12;
    const int n   = hh / 3;
    const int ks  = hh % 3;
    const int slot = (ks == 0) ? 0 : (ks == 1 ? 1 + (ph & 1) : 3 + (ph & 3));
    const int q0  = blockIdx.x * 64;

    const float* Qp = qkvb + (size_t)zbl * (1024 * 384);
    const float* Kp = Qp + 128;
    const float* Vp = Qp + 256;

    const int tid = threadIdx.x;
    const int tx  = tid & 15;
    const int ty  = tid >> 4;

    for (int f = tid; f < 2048; f += 256) {
        int r = f >> 5, c4 = (f & 31) << 2;
        float4 v = *(const float4*)(Qp + (size_t)(q0 + r) * 384 + c4);
        Qs[c4 + 0][r] = v.x; Qs[c4 + 1][r] = v.y;
        Qs[c4 + 2][r] = v.z; Qs[c4 + 3][r] = v.w;
    }

    float m_i[4], l_i[4], O[4][8];
#pragma unroll
    for (int i = 0; i < 4; ++i) {
        m_i[i] = -1e30f; l_i[i] = 0.f;
#pragma unroll
        for (int j = 0; j < 8; ++j) O[i][j] = 0.f;
    }
    const float sc = 0.08838834764831845f;

    const int jend = q0 + 32;
    for (int j0 = 0; j0 <= jend; j0 += 32) {
        for (int f = tid; f < 1024; f += 256) {
            int r = f >> 5, c4 = (f & 31) << 2;
            float4 v = *(const float4*)(Kp + (size_t)(j0 + r) * 384 + c4);
            KV[(c4 + 0) * 36 + r] = v.x; KV[(c4 + 1) * 36 + r] = v.y;
            KV[(c4 + 2) * 36 + r] = v.z; KV[(c4 + 3) * 36 + r] = v.w;
        }
        __syncthreads();

        float S[4][2] = {{0.f, 0.f}, {0.f, 0.f}, {0.f, 0.f}, {0.f, 0.f}};
#pragma unroll 4
        for (int d = 0; d < 128; ++d) {
            float a[4];
            *(float4*)a = *(const float4*)&Qs[d][ty * 4];
            float2 bb = *(const float2*)&KV[d * 36 + tx * 2];
#pragma unroll
            for (int i = 0; i < 4; ++i) {
                S[i][0] = fmaf(a[i], bb.x, S[i][0]);
                S[i][1] = fmaf(a[i], bb.y, S[i][1]);
            }
        }

        const bool need_mask = (j0 + 31 > q0);
        float alpha[4];
#pragma unroll
        for (int i = 0; i < 4; ++i) {
            int tq = q0 + ty * 4 + i;
            float s0 = S[i][0] * sc, s1 = S[i][1] * sc;
            if (need_mask) {
                if (j0 + tx * 2 + 0 > tq) s0 = -1e30f;
                if (j0 + tx * 2 + 1 > tq) s1 = -1e30f;
            }
            float mx = fmaxf(s0, s1);
#pragma unroll
            for (int msk = 8; msk; msk >>= 1) mx = fmaxf(mx, __shfl_xor(mx, msk, 16));
            float mnew = fmaxf(m_i[i], mx);
            float al   = expf(m_i[i] - mnew);
            s0 = expf(s0 - mnew); s1 = expf(s1 - mnew);
            float rs = s0 + s1;
#pragma unroll
            for (int msk = 8; msk; msk >>= 1) rs += __shfl_xor(rs, msk, 16);
            l_i[i]  = l_i[i] * al + rs;
            m_i[i]  = mnew;
            alpha[i] = al;
            S[i][0] = s0; S[i][1] = s1;
        }
#pragma unroll
        for (int j = 0; j < 2; ++j) {
            float4 col;
            col.x = S[0][j]; col.y = S[1][j]; col.z = S[2][j]; col.w = S[3][j];
            *(float4*)&PsT[tx * 2 + j][ty * 4] = col;
        }
#pragma unroll
        for (int i = 0; i < 4; ++i)
#pragma unroll
            for (int j = 0; j < 8; ++j) O[i][j] *= alpha[i];
        __syncthreads();

        for (int f = tid; f < 1024; f += 256) {
            int r = f >> 5, c4 = (f & 31) << 2;
            float4 v = *(const float4*)(Vp + (size_t)(j0 + r) * 384 + c4);
            *(float4*)&KV[r * 132 + c4] = v;
        }
        __syncthreads();

#pragma unroll 4
        for (int kv = 0; kv < 32; ++kv) {
            float p[4];
            *(float4*)p = *(const float4*)&PsT[kv][ty * 4];
            float vv[8];
            *(float4*)&vv[0] = *(const float4*)&KV[kv * 132 + tx * 8];
            *(float4*)&vv[4] = *(const float4*)&KV[kv * 132 + tx * 8 + 4];
#pragma unroll
            for (int i = 0; i < 4; ++i)
#pragma unroll
                for (int j = 0; j < 8; ++j) O[i][j] = fmaf(p[i], vv[j], O[i][j]);
        }
        __syncthreads();
    }

#pragma unroll
    for (int i = 0; i < 4; ++i) {
        int t = q0 + ty * 4 + i;
        float inv = 1.0f / l_i[i];
        float* dst = z + (size_t)(b * 1024 + t) * ND + n * DD + slot * DH + tx * 8;
#pragma unroll
        for (int j = 0; j < 8; ++j) dst[j] += O[i][j] * inv;
    }
}

// ---------------------------------------------------------------------------
// Launcher. WS peak: z 117.4 MB + max(attn 50.3 MB, mixer 49.5 MB) < 191 MB.
// ---------------------------------------------------------------------------
extern "C" void kernel_launch(void* const* d_in, const int* in_sizes, int n_in,
                              void* d_out, int out_size, void* d_ws, size_t ws_size,
                              hipStream_t stream)
{
    const float* x          = (const float*)d_in[0];
    const float* enc_base_w = (const float*)d_in[1];
    const float* enc_A_w    = (const float*)d_in[2];
    const float* enc_B      = (const float*)d_in[3];
    const float* enc_beta   = (const float*)d_in[4];
    const float* Wqkv       = (const float*)d_in[5];
    const float* ln_attn_s  = (const float*)d_in[6];
    const float* ln_attn_b  = (const float*)d_in[7];
    const float* ln_mix_s   = (const float*)d_in[8];
    const float* ln_mix_b   = (const float*)d_in[9];
    const float* w1         = (const float*)d_in[10];
    const float* b1         = (const float*)d_in[11];
    const float* w2         = (const float*)d_in[12];
    const float* b2         = (const float*)d_in[13];
    const float* dec_ln_s   = (const float*)d_in[14];
    const float* dec_ln_b   = (const float*)d_in[15];
    const float* dec_down   = (const float*)d_in[16];
    const float* dec_up     = (const float*)d_in[17];
    const int*   phase_p    = (const int*)d_in[18];
    float* out = (float*)d_out;

    float* ws = (float*)d_ws;
    float* z  = ws;                                  // 8192*3584 fp32 (persistent)
    float* R  = ws + (size_t)BT * ND;                // reusable region
    // enc phase
    float* hbuf = R;                                 // 8192*64 fp32
    // attn phase (per group of 24 heads)
    float* xh   = R;                                 // 24*1024*128 fp32
    float* qkvb = R + (size_t)24 * 1024 * 128;       // 24*1024*384 fp32
    // mixer phase (bf16)
    __hip_bfloat16* w1b  = (__hip_bfloat16*)R;       // 3584*896
    __hip_bfloat16* w2b  = w1b + (size_t)HID * DD;   // 896*3584
    __hip_bfloat16* hm   = w2b + (size_t)DD * HID;   // 4096*896   (chunk)
    __hip_bfloat16* gbuf = hm + (size_t)4096 * DD;   // 4096*3584  (chunk)
    // dec phase
    float* t1   = R;                                 // 8192*64 fp32

    // --- Encoder (fp32)
    gemm_kernel<64, 64, 16, 4, 4, false, 0>
        <<<dim3(1, 128), 256, 0, stream>>>(x, enc_A_w, hbuf, RK, IO, nullptr, nullptr);
    gemm_kernel<128, 128, 16, 8, 8, false, 4>
        <<<dim3(7, 64), 256, 0, stream>>>(x, enc_base_w, z, DD, IO, nullptr, nullptr);
    gemm_kernel<128, 128, 16, 8, 8, true, 5>
        <<<dim3(28, 64), 256, 0, stream>>>(hbuf, enc_B, z, ND, RK, nullptr, enc_beta);

    // --- Attention in 4 groups of 24 heads (fp32)
    for (int g = 0; g < 4; ++g) {
        ln_attn_kernel<<<dim3(6144), 256, 0, stream>>>(z, xh, ln_attn_s, ln_attn_b,
                                                       phase_p, g * 2048);
        qkv_kernel<<<dim3(3, 8, 24), 256, 0, stream>>>(xh, Wqkv, qkvb, phase_p, g * 24);
        flash_attn_kernel<<<dim3(16, 24), 256, 0, stream>>>(qkvb, z, phase_p, g * 24);
    }

    // --- Mixer MLP on bf16 MFMA, 8 row-chunks of 4096 (of 32768 x 896)
    cvt_bf16_kernel<<<dim3(3136), 256, 0, stream>>>(w1, w1b, HID * DD / 4);
    cvt_bf16_kernel<<<dim3(3136), 256, 0, stream>>>(w2, w2b, DD * HID / 4);
    for (int c = 0; c < 8; ++c) {
        float* zc = z + (size_t)c * 4096 * DD;
        ln_row_bf16_kernel<<<dim3(4096), 256, 0, stream>>>(zc, hm, ln_mix_s, ln_mix_b);
        gemm_bf16_kernel<1><<<dim3(28, 32), 256, 0, stream>>>(hm, w1b, nullptr, gbuf,
                                                              HID, DD, b1);
        gemm_bf16_kernel<2><<<dim3(7, 32), 256, 0, stream>>>(gbuf, w2b, zc, nullptr,
                                                             DD, HID, b2);
    }

    // --- Decoder (fp32): LN in place, then low-rank down/up
    ln_row_kernel<3584><<<dim3(8192), 256, 0, stream>>>(z, z, dec_ln_s, dec_ln_b);
    gemm_kernel<64, 64, 16, 4, 4, false, 0>
        <<<dim3(1, 128), 256, 0, stream>>>(z, dec_down, t1, RK, ND, nullptr, nullptr);
    gemm_kernel<128, 128, 16, 8, 8, false, 0>
        <<<dim3(8, 64), 256, 0, stream>>>(t1, dec_up, out, IO, RK, nullptr, nullptr);
}

// Round 4
// 2293.423 us; speedup vs baseline: 4.5353x; 1.6086x over previous
//
#include <hip/hip_runtime.h>
#include <hip/hip_bf16.h>
#include <math.h>

// ---------------------------------------------------------------------------
// Morpher forward. Mixer MLP + attention (QKV, flash) + encoder base GEMM on
// bf16 MFMA; small GEMMs and LNs fp32.
// Shapes: B=8 T=1024 (BT=8192), N=4, K=3, S=7, DH=128, D=896, ND=3584,
// IO=1024, RANK=64, HIDDEN=3584.
// Phase tables (device-side, phase read from d_in[18]):
//   slot[k]  = {0, 1+(ph&1), 3+(ph&3)}
//   PERM[ph][k][n]: k==0 -> n ; k==1 -> (n+2*(ph&1))&3 ; k==2 -> (n+(ph&3))&3
// ---------------------------------------------------------------------------

#define BT   8192
#define DH   128
#define DD   896
#define ND   3584
#define IO   1024
#define RK   64
#define HID  3584

typedef __attribute__((ext_vector_type(8))) short short8;
typedef __attribute__((ext_vector_type(4))) float f32x4;
typedef __hip_bfloat16 bf16;

// ---------------------------------------------------------------------------
// fp32 tiled GEMM (encoder G1/G3, decoder).
//  EPI 0: C = acc      EPI 5: C += sp[0] * acc
// ---------------------------------------------------------------------------
template<int BM, int BN, int BK, int TM, int TN, bool BKN, int EPI>
__global__ __launch_bounds__(256) void gemm_kernel(const float* __restrict__ A,
                                                   const float* __restrict__ B,
                                                   float* __restrict__ C,
                                                   int N, int Kd,
                                                   const float* __restrict__ sp)
{
    constexpr int THREADS = (BM / TM) * (BN / TN);
    constexpr int LDA = BM + 4;
    constexpr int LDB = BN + 4;
    __shared__ float As[BK][LDA];
    __shared__ float Bs[BK][LDB];

    const int tid = threadIdx.x;
    constexpr int NX = BN / TN;
    const int tx = tid % NX;
    const int ty = tid / NX;
    const int row0 = blockIdx.y * BM;
    const int col0 = blockIdx.x * BN;

    float acc[TM][TN];
#pragma unroll
    for (int i = 0; i < TM; ++i)
#pragma unroll
        for (int j = 0; j < TN; ++j) acc[i][j] = 0.f;

    for (int k0 = 0; k0 < Kd; k0 += BK) {
        constexpr int AF4 = BM * BK / 4;
        for (int f = tid; f < AF4; f += THREADS) {
            int r  = f / (BK / 4);
            int c4 = (f % (BK / 4)) * 4;
            float4 v = *(const float4*)(A + (size_t)(row0 + r) * Kd + k0 + c4);
            As[c4 + 0][r] = v.x; As[c4 + 1][r] = v.y;
            As[c4 + 2][r] = v.z; As[c4 + 3][r] = v.w;
        }
        if (BKN) {
            constexpr int BF4 = BK * BN / 4;
            for (int f = tid; f < BF4; f += THREADS) {
                int r  = f / (BN / 4);
                int c4 = (f % (BN / 4)) * 4;
                *(float4*)&Bs[r][c4] =
                    *(const float4*)(B + (size_t)(k0 + r) * N + col0 + c4);
            }
        } else {
            constexpr int BF4 = BN * BK / 4;
            for (int f = tid; f < BF4; f += THREADS) {
                int r  = f / (BK / 4);
                int c4 = (f % (BK / 4)) * 4;
                float4 v = *(const float4*)(B + (size_t)(col0 + r) * Kd + k0 + c4);
                Bs[c4 + 0][r] = v.x; Bs[c4 + 1][r] = v.y;
                Bs[c4 + 2][r] = v.z; Bs[c4 + 3][r] = v.w;
            }
        }
        __syncthreads();

#pragma unroll
        for (int kk = 0; kk < BK; ++kk) {
            float a[TM], b[TN];
#pragma unroll
            for (int i = 0; i < TM; i += 4)
                *(float4*)&a[i] = *(const float4*)&As[kk][ty * TM + i];
#pragma unroll
            for (int j = 0; j < TN; j += 4)
                *(float4*)&b[j] = *(const float4*)&Bs[kk][tx * TN + j];
#pragma unroll
            for (int i = 0; i < TM; ++i)
#pragma unroll
                for (int j = 0; j < TN; ++j)
                    acc[i][j] = fmaf(a[i], b[j], acc[i][j]);
        }
        __syncthreads();
    }

    const int crow = row0 + ty * TM;
    const int ccol = col0 + tx * TN;
    if (EPI == 0) {
#pragma unroll
        for (int i = 0; i < TM; ++i) {
            float* cp = C + (size_t)(crow + i) * N + ccol;
#pragma unroll
            for (int j = 0; j < TN; ++j) cp[j] = acc[i][j];
        }
    } else { // EPI == 5
        float beta = sp[0];
#pragma unroll
        for (int i = 0; i < TM; ++i) {
            float* cp = C + (size_t)(crow + i) * N + ccol;
#pragma unroll
            for (int j = 0; j < TN; ++j) cp[j] += beta * acc[i][j];
        }
    }
}

// ---------------------------------------------------------------------------
// bf16 MFMA GEMM: C(MxN) = A(MxK bf16 rm) @ B(NxK bf16 rm)^T
// Block 128x128, 4 waves (2x2), wave 64x64 via 4x4 mfma_f32_16x16x32_bf16.
// BK=64, global_load_lds width-16, unpadded [row][k] LDS.
//  EPI 1: Cb = bf16(gelu(acc + bias[col]))
//  EPI 2: Cf += acc + bias[col]
//  EPI 3: replicate: Cf[row*ND + n*896 + col] = acc, n=0..3 (z0 base; col<896)
// ---------------------------------------------------------------------------
template<int EPI>
__global__ __launch_bounds__(256) void gemm_bf16_kernel(
    const bf16* __restrict__ A,
    const bf16* __restrict__ B,
    float* __restrict__ Cf,
    bf16* __restrict__ Cb,
    int N, int Kd,
    const float* __restrict__ bias)
{
    __shared__ bf16 As[128 * 64];
    __shared__ bf16 Bs[128 * 64];

    const int tid  = threadIdx.x;
    const int wave = tid >> 6;
    const int lane = tid & 63;
    const int wm = wave >> 1, wn = wave & 1;
    const int row0 = blockIdx.y * 128;
    const int col0 = blockIdx.x * 128;
    const int lr = lane & 15;
    const int lq = lane >> 4;
    const int srow = lane >> 3;
    const int scol = (lane & 7) * 8;

    f32x4 acc[4][4];
#pragma unroll
    for (int i = 0; i < 4; ++i)
#pragma unroll
        for (int j = 0; j < 4; ++j) acc[i][j] = (f32x4){0.f, 0.f, 0.f, 0.f};

    for (int k0 = 0; k0 < Kd; k0 += 64) {
#pragma unroll
        for (int j = 0; j < 4; ++j) {
            const int rg = wave * 32 + j * 8;
            __builtin_amdgcn_global_load_lds(
                (const __attribute__((address_space(1))) unsigned int*)
                    (A + (size_t)(row0 + rg + srow) * Kd + k0 + scol),
                (__attribute__((address_space(3))) unsigned int*)(As + rg * 64),
                16, 0, 0);
        }
#pragma unroll
        for (int j = 0; j < 4; ++j) {
            const int rg = wave * 32 + j * 8;
            __builtin_amdgcn_global_load_lds(
                (const __attribute__((address_space(1))) unsigned int*)
                    (B + (size_t)(col0 + rg + srow) * Kd + k0 + scol),
                (__attribute__((address_space(3))) unsigned int*)(Bs + rg * 64),
                16, 0, 0);
        }
        __syncthreads();

#pragma unroll
        for (int s = 0; s < 64; s += 32) {
            short8 af[4], bf[4];
#pragma unroll
            for (int mt = 0; mt < 4; ++mt)
                af[mt] = *(const short8*)&As[(wm * 64 + mt * 16 + lr) * 64 + s + lq * 8];
#pragma unroll
            for (int nt = 0; nt < 4; ++nt)
                bf[nt] = *(const short8*)&Bs[(wn * 64 + nt * 16 + lr) * 64 + s + lq * 8];
#pragma unroll
            for (int mt = 0; mt < 4; ++mt)
#pragma unroll
                for (int nt = 0; nt < 4; ++nt)
                    acc[mt][nt] = __builtin_amdgcn_mfma_f32_16x16x32_bf16(
                        af[mt], bf[nt], acc[mt][nt], 0, 0, 0);
        }
        __syncthreads();
    }

#pragma unroll
    for (int mt = 0; mt < 4; ++mt) {
#pragma unroll
        for (int nt = 0; nt < 4; ++nt) {
            const int col = col0 + wn * 64 + nt * 16 + lr;
            const float bcol = (EPI == 3) ? 0.f : bias[col];
#pragma unroll
            for (int r = 0; r < 4; ++r) {
                const int row = row0 + wm * 64 + mt * 16 + lq * 4 + r;
                float v = acc[mt][nt][r] + bcol;
                if (EPI == 1) {
                    v = 0.5f * v * (1.0f + erff(v * 0.70710678118654752f));
                    Cb[(size_t)row * N + col] = __float2bfloat16(v);
                } else if (EPI == 2) {
                    Cf[(size_t)row * N + col] += v;
                } else { // EPI == 3
                    float* cp = Cf + (size_t)row * ND;
#pragma unroll
                    for (int n4 = 0; n4 < 4; ++n4) cp[n4 * DD + col] = v;
                }
            }
        }
    }
}

// ---------------------------------------------------------------------------
// QKV bf16 MFMA + transposed V emission.
//  A = xh[zbl] (1024x128 bf16), B = Wt[k*4+m] (384x128 bf16 = W^T),
//  cols <256 -> qkvb bf16 [zbl][1024][384]; cols>=256 -> Vtg[zbl][d][t] bf16.
// grid (3, 8, 48)
// ---------------------------------------------------------------------------
__global__ __launch_bounds__(256) void qkv_bf16_kernel(
    const bf16* __restrict__ xh,
    const bf16* __restrict__ Wt,
    bf16* __restrict__ qkvb,
    bf16* __restrict__ Vtg,
    const int* __restrict__ phase_p,
    int go)
{
    __shared__ bf16 As[128 * 64];
    __shared__ bf16 Bs[128 * 64];

    const int ph  = phase_p[0] & 3;
    const int zbl = blockIdx.z;
    const int hh  = (go + zbl) % 12;
    const int n   = hh / 3;
    const int k   = hh % 3;
    const int m   = (k == 0) ? n
                  : (k == 1) ? ((n + 2 * (ph & 1)) & 3)
                             : ((n + (ph & 3)) & 3);
    const bf16* A  = xh + (size_t)zbl * (1024 * 128);
    const bf16* Bw = Wt + (size_t)(k * 4 + m) * (384 * 128);

    const int tid  = threadIdx.x;
    const int wave = tid >> 6;
    const int lane = tid & 63;
    const int wm = wave >> 1, wn = wave & 1;
    const int row0 = blockIdx.y * 128;
    const int col0 = blockIdx.x * 128;
    const int lr = lane & 15;
    const int lq = lane >> 4;
    const int srow = lane >> 3;
    const int scol = (lane & 7) * 8;

    f32x4 acc[4][4];
#pragma unroll
    for (int i = 0; i < 4; ++i)
#pragma unroll
        for (int j = 0; j < 4; ++j) acc[i][j] = (f32x4){0.f, 0.f, 0.f, 0.f};

#pragma unroll
    for (int k0 = 0; k0 < 128; k0 += 64) {
#pragma unroll
        for (int j = 0; j < 4; ++j) {
            const int rg = wave * 32 + j * 8;
            __builtin_amdgcn_global_load_lds(
                (const __attribute__((address_space(1))) unsigned int*)
                    (A + (size_t)(row0 + rg + srow) * 128 + k0 + scol),
                (__attribute__((address_space(3))) unsigned int*)(As + rg * 64),
                16, 0, 0);
        }
#pragma unroll
        for (int j = 0; j < 4; ++j) {
            const int rg = wave * 32 + j * 8;
            __builtin_amdgcn_global_load_lds(
                (const __attribute__((address_space(1))) unsigned int*)
                    (Bw + (size_t)(col0 + rg + srow) * 128 + k0 + scol),
                (__attribute__((address_space(3))) unsigned int*)(Bs + rg * 64),
                16, 0, 0);
        }
        __syncthreads();

#pragma unroll
        for (int s = 0; s < 64; s += 32) {
            short8 af[4], bf[4];
#pragma unroll
            for (int mt = 0; mt < 4; ++mt)
                af[mt] = *(const short8*)&As[(wm * 64 + mt * 16 + lr) * 64 + s + lq * 8];
#pragma unroll
            for (int nt = 0; nt < 4; ++nt)
                bf[nt] = *(const short8*)&Bs[(wn * 64 + nt * 16 + lr) * 64 + s + lq * 8];
#pragma unroll
            for (int mt = 0; mt < 4; ++mt)
#pragma unroll
                for (int nt = 0; nt < 4; ++nt)
                    acc[mt][nt] = __builtin_amdgcn_mfma_f32_16x16x32_bf16(
                        af[mt], bf[nt], acc[mt][nt], 0, 0, 0);
        }
        __syncthreads();
    }

    if (col0 < 256) {
        bf16* C = qkvb + (size_t)zbl * (1024 * 384);
#pragma unroll
        for (int mt = 0; mt < 4; ++mt)
#pragma unroll
            for (int nt = 0; nt < 4; ++nt) {
                const int col = col0 + wn * 64 + nt * 16 + lr;
#pragma unroll
                for (int r = 0; r < 4; ++r) {
                    const int row = row0 + wm * 64 + mt * 16 + lq * 4 + r;
                    C[(size_t)row * 384 + col] = __float2bfloat16(acc[mt][nt][r]);
                }
            }
    } else {
        bf16* Vt = Vtg + (size_t)zbl * (128 * 1024);
#pragma unroll
        for (int mt = 0; mt < 4; ++mt)
#pragma unroll
            for (int nt = 0; nt < 4; ++nt) {
                const int d = col0 - 256 + wn * 64 + nt * 16 + lr;
                const int rowb = row0 + wm * 64 + mt * 16 + lq * 4;
                union { bf16 h[4]; uint2 u; } pk;
#pragma unroll
                for (int r = 0; r < 4; ++r)
                    pk.h[r] = __float2bfloat16(acc[mt][nt][r]);
                *(uint2*)(Vt + (size_t)d * 1024 + rowb) = pk.u;
            }
    }
}

// ---------------------------------------------------------------------------
// Flash attention bf16 MFMA: grid (8 q-tiles, 48 heads), 256 threads.
// BQ=128 (wave: 32 rows), BKV=64. K and V^T share one LDS buffer.
// LDS: Qs 32K + KVs 16K + Ps 16K = 64K.
// ---------------------------------------------------------------------------
__global__ __launch_bounds__(256) void flash_bf16_kernel(
    const bf16* __restrict__ qkvb,
    const bf16* __restrict__ Vtg,
    float* __restrict__ z,
    const int* __restrict__ phase_p,
    int go)
{
    __shared__ bf16 Qs[128 * 128];
    __shared__ bf16 KVs[64 * 128];
    __shared__ bf16 Ps[128 * 64];

    const int ph  = phase_p[0] & 3;
    const int zbl = blockIdx.y;
    const int zb  = go + zbl;
    const int b   = zb / 12;
    const int hh  = zb % 12;
    const int n   = hh / 3;
    const int ks  = hh % 3;
    const int slot = (ks == 0) ? 0 : (ks == 1 ? 1 + (ph & 1) : 3 + (ph & 3));
    const int q0  = blockIdx.x * 128;

    const bf16* Qp = qkvb + (size_t)zbl * (1024 * 384);
    const bf16* Kp = Qp + 128;
    const bf16* Vp = Vtg + (size_t)zbl * (128 * 1024);

    const int tid  = threadIdx.x;
    const int wave = tid >> 6;
    const int lane = tid & 63;
    const int lr = lane & 15;
    const int lq = lane >> 4;
    // staging maps
    const int sr4 = lane >> 4, sc4 = (lane & 15) * 8;   // 256B rows (Q,K)
    const int sr8 = lane >> 3, sc8 = (lane & 7) * 8;    // 128B rows (V^T)

    // load Q tile (128 x 128), wave loads its own 32 rows
#pragma unroll
    for (int j = 0; j < 8; ++j) {
        const int rg = wave * 32 + j * 4;
        __builtin_amdgcn_global_load_lds(
            (const __attribute__((address_space(1))) unsigned int*)
                (Qp + (size_t)(q0 + rg + sr4) * 384 + sc4),
            (__attribute__((address_space(3))) unsigned int*)(Qs + rg * 128),
            16, 0, 0);
    }

    f32x4 accO[2][8];
    float m_i[2][4], l_i[2][4];
#pragma unroll
    for (int mt = 0; mt < 2; ++mt) {
#pragma unroll
        for (int j = 0; j < 8; ++j) accO[mt][j] = (f32x4){0.f, 0.f, 0.f, 0.f};
#pragma unroll
        for (int r = 0; r < 4; ++r) { m_i[mt][r] = -1e30f; l_i[mt][r] = 0.f; }
    }
    const float sc = 0.08838834764831845f;   // 1/sqrt(128)

    const int jend = q0 + 64;
    for (int j0 = 0; j0 <= jend; j0 += 64) {
        // K tile [64][128]
#pragma unroll
        for (int j = 0; j < 4; ++j) {
            const int rg = wave * 16 + j * 4;
            __builtin_amdgcn_global_load_lds(
                (const __attribute__((address_space(1))) unsigned int*)
                    (Kp + (size_t)(j0 + rg + sr4) * 384 + sc4),
                (__attribute__((address_space(3))) unsigned int*)(KVs + rg * 128),
                16, 0, 0);
        }
        __syncthreads();

        // S = Q K^T (wave: 32 q x 64 kv)
        f32x4 accS[2][4];
#pragma unroll
        for (int mt = 0; mt < 2; ++mt)
#pragma unroll
            for (int nt = 0; nt < 4; ++nt) accS[mt][nt] = (f32x4){0.f, 0.f, 0.f, 0.f};
#pragma unroll
        for (int s = 0; s < 128; s += 32) {
            short8 aq[2], bk[4];
#pragma unroll
            for (int mt = 0; mt < 2; ++mt)
                aq[mt] = *(const short8*)&Qs[(wave * 32 + mt * 16 + lr) * 128 + s + lq * 8];
#pragma unroll
            for (int nt = 0; nt < 4; ++nt)
                bk[nt] = *(const short8*)&KVs[(nt * 16 + lr) * 128 + s + lq * 8];
#pragma unroll
            for (int mt = 0; mt < 2; ++mt)
#pragma unroll
                for (int nt = 0; nt < 4; ++nt)
                    accS[mt][nt] = __builtin_amdgcn_mfma_f32_16x16x32_bf16(
                        aq[mt], bk[nt], accS[mt][nt], 0, 0, 0);
        }

        // online softmax; rows owned: q0 + wave*32 + mt*16 + lq*4 + r
        const bool need_mask = (j0 + 63 > q0);
#pragma unroll
        for (int mt = 0; mt < 2; ++mt) {
#pragma unroll
            for (int r = 0; r < 4; ++r) {
                const int row = q0 + wave * 32 + mt * 16 + lq * 4 + r;
                float sv[4];
#pragma unroll
                for (int nt = 0; nt < 4; ++nt) {
                    float v = accS[mt][nt][r] * sc;
                    if (need_mask && (j0 + nt * 16 + lr > row)) v = -1e30f;
                    sv[nt] = v;
                }
                float mx = fmaxf(fmaxf(sv[0], sv[1]), fmaxf(sv[2], sv[3]));
#pragma unroll
                for (int msk = 8; msk; msk >>= 1) mx = fmaxf(mx, __shfl_xor(mx, msk, 16));
                float mnew = fmaxf(m_i[mt][r], mx);
                float al   = __expf(m_i[mt][r] - mnew);
                float rs = 0.f;
#pragma unroll
                for (int nt = 0; nt < 4; ++nt) {
                    sv[nt] = __expf(sv[nt] - mnew);
                    rs += sv[nt];
                }
#pragma unroll
                for (int msk = 8; msk; msk >>= 1) rs += __shfl_xor(rs, msk, 16);
                l_i[mt][r] = l_i[mt][r] * al + rs;
                m_i[mt][r] = mnew;
                // scale O rows by alpha
#pragma unroll
                for (int d8 = 0; d8 < 8; ++d8) accO[mt][d8][r] *= al;
                // write P row chunk to LDS (bf16)
                const int prow = wave * 32 + mt * 16 + lq * 4 + r;
#pragma unroll
                for (int nt = 0; nt < 4; ++nt)
                    Ps[prow * 64 + nt * 16 + lr] = __float2bfloat16(sv[nt]);
            }
        }
        __syncthreads();   // K reads done by all waves; Ps written

        // V^T tile [128][64] into KVs
#pragma unroll
        for (int j = 0; j < 4; ++j) {
            const int rg = wave * 32 + j * 8;
            __builtin_amdgcn_global_load_lds(
                (const __attribute__((address_space(1))) unsigned int*)
                    (Vp + (size_t)(rg + sr8) * 1024 + j0 + sc8),
                (__attribute__((address_space(3))) unsigned int*)(KVs + rg * 64),
                16, 0, 0);
        }
        __syncthreads();

        // O += P V  (wave: 32 q x 128 d)
#pragma unroll
        for (int kvs = 0; kvs < 64; kvs += 32) {
            short8 ap[2], bv[8];
#pragma unroll
            for (int mt = 0; mt < 2; ++mt)
                ap[mt] = *(const short8*)&Ps[(wave * 32 + mt * 16 + lr) * 64 + kvs + lq * 8];
#pragma unroll
            for (int d8 = 0; d8 < 8; ++d8)
                bv[d8] = *(const short8*)&KVs[(d8 * 16 + lr) * 64 + kvs + lq * 8];
#pragma unroll
            for (int mt = 0; mt < 2; ++mt)
#pragma unroll
                for (int d8 = 0; d8 < 8; ++d8)
                    accO[mt][d8] = __builtin_amdgcn_mfma_f32_16x16x32_bf16(
                        ap[mt], bv[d8], accO[mt][d8], 0, 0, 0);
        }
        __syncthreads();   // V reads done before next K load
    }

    // epilogue: z += O / l at head slot
#pragma unroll
    for (int mt = 0; mt < 2; ++mt) {
#pragma unroll
        for (int r = 0; r < 4; ++r) {
            const int t = q0 + wave * 32 + mt * 16 + lq * 4 + r;
            const float inv = 1.0f / l_i[mt][r];
            float* dst = z + (size_t)(b * 1024 + t) * ND + n * DD + slot * DH;
#pragma unroll
            for (int d8 = 0; d8 < 8; ++d8)
                dst[d8 * 16 + lr] += accO[mt][d8][r] * inv;
        }
    }
}

// ---------------------------------------------------------------------------
// fp32 -> bf16 elementwise (n4 = n/4)
// ---------------------------------------------------------------------------
__global__ __launch_bounds__(256) void cvt_bf16_kernel(const float* __restrict__ src,
                                                       bf16* __restrict__ dst,
                                                       int n4)
{
    int i = blockIdx.x * 256 + threadIdx.x;
    if (i < n4) {
        float4 v = ((const float4*)src)[i];
        bf16* d = dst + (size_t)i * 4;
        d[0] = __float2bfloat16(v.x);
        d[1] = __float2bfloat16(v.y);
        d[2] = __float2bfloat16(v.z);
        d[3] = __float2bfloat16(v.w);
    }
}

// Wqkv (12,128,384) fp32 -> Wt (12,384,128) bf16
__global__ __launch_bounds__(256) void cvt_wqkv_kernel(const float* __restrict__ W,
                                                       bf16* __restrict__ Wt)
{
    int o = blockIdx.x * 256 + threadIdx.x;
    if (o < 12 * 384 * 128) {
        int i = o / 49152, rem = o % 49152;
        int e = rem / 128, d = rem % 128;
        Wt[o] = __float2bfloat16(W[(size_t)i * 49152 + d * 384 + e]);
    }
}

// ---------------------------------------------------------------------------
// Attention-input LayerNorm -> bf16 head-major xh (group of 4 batches).
// grid = 12288 blocks (49152 rows / 4 waves)
// ---------------------------------------------------------------------------
__global__ __launch_bounds__(256) void ln_attn_kernel(const float* __restrict__ z,
                                                      bf16* __restrict__ xh,
                                                      const float* __restrict__ scale,
                                                      const float* __restrict__ bias,
                                                      const int* __restrict__ phase_p,
                                                      int bt0)
{
    const int ph   = phase_p[0] & 3;
    const int lane = threadIdx.x & 63;
    const int row  = blockIdx.x * 4 + (threadIdx.x >> 6);
    const int k    = row % 3;
    const int n    = (row / 3) & 3;
    const int btl  = row / 12;                            // [0, 4096)
    const int slot = (k == 0) ? 0 : (k == 1 ? 1 + (ph & 1) : 3 + (ph & 3));
    const int bt   = bt0 + btl;

    const float* src = z + (size_t)bt * ND + n * DD + slot * DH + lane * 2;
    float2 v = *(const float2*)src;
    float s = v.x + v.y;
    float q = v.x * v.x + v.y * v.y;
#pragma unroll
    for (int m = 32; m; m >>= 1) { s += __shfl_xor(s, m); q += __shfl_xor(q, m); }
    float mu  = s * (1.0f / 128.0f);
    float var = q * (1.0f / 128.0f) - mu * mu;
    float r   = rsqrtf(var + 1e-5f);

    float2 sc2 = *(const float2*)(scale + lane * 2);
    float2 bi2 = *(const float2*)(bias + lane * 2);
    const int bl = btl >> 10, t = btl & 1023;
    union { bf16 h[2]; unsigned int u; } pk;
    pk.h[0] = __float2bfloat16((v.x - mu) * r * sc2.x + bi2.x);
    pk.h[1] = __float2bfloat16((v.y - mu) * r * sc2.y + bi2.y);
    *(unsigned int*)(xh + (size_t)((bl * 12 + n * 3 + k) * 1024 + t) * DH + lane * 2) = pk.u;
}

// ---------------------------------------------------------------------------
// Row LayerNorm fp32 out (W=3584 decoder), safe in-place.
// ---------------------------------------------------------------------------
template<int W>
__global__ __launch_bounds__(256) void ln_row_kernel(const float* __restrict__ in,
                                                     float* __restrict__ outp,
                                                     const float* __restrict__ scale,
                                                     const float* __restrict__ bias)
{
    constexpr int NIT = (W + 255) / 256;
    const int row = blockIdx.x;
    const int tid = threadIdx.x;
    const float* rp = in + (size_t)row * W;

    float v[NIT];
    float s = 0.f, q = 0.f;
#pragma unroll
    for (int i = 0; i < NIT; ++i) {
        int idx = tid + i * 256;
        if (idx < W) { float t = rp[idx]; v[i] = t; s += t; q += t * t; }
        else v[i] = 0.f;
    }
#pragma unroll
    for (int m = 32; m; m >>= 1) { s += __shfl_xor(s, m); q += __shfl_xor(q, m); }
    __shared__ float ss[4], sq[4];
    if ((tid & 63) == 0) { ss[tid >> 6] = s; sq[tid >> 6] = q; }
    __syncthreads();
    s = ss[0] + ss[1] + ss[2] + ss[3];
    q = sq[0] + sq[1] + sq[2] + sq[3];
    float mu  = s * (1.0f / W);
    float var = q * (1.0f / W) - mu * mu;
    float r   = rsqrtf(var + 1e-5f);

    float* op = outp + (size_t)row * W;
#pragma unroll
    for (int i = 0; i < NIT; ++i) {
        int idx = tid + i * 256;
        if (idx < W) op[idx] = (v[i] - mu) * r * scale[idx] + bias[idx];
    }
}

// ---------------------------------------------------------------------------
// Row LayerNorm, W=896, bf16 output (mixer input).
// ---------------------------------------------------------------------------
__global__ __launch_bounds__(256) void ln_row_bf16_kernel(const float* __restrict__ in,
                                                          bf16* __restrict__ outp,
                                                          const float* __restrict__ scale,
                                                          const float* __restrict__ bias)
{
    constexpr int W = 896, NIT = 4;
    const int row = blockIdx.x;
    const int tid = threadIdx.x;
    const float* rp = in + (size_t)row * W;

    float v[NIT];
    float s = 0.f, q = 0.f;
#pragma unroll
    for (int i = 0; i < NIT; ++i) {
        int idx = tid + i * 256;
        if (idx < W) { float t = rp[idx]; v[i] = t; s += t; q += t * t; }
        else v[i] = 0.f;
    }
#pragma unroll
    for (int m = 32; m; m >>= 1) { s += __shfl_xor(s, m); q += __shfl_xor(q, m); }
    __shared__ float ss[4], sq[4];
    if ((tid & 63) == 0) { ss[tid >> 6] = s; sq[tid >> 6] = q; }
    __syncthreads();
    s = ss[0] + ss[1] + ss[2] + ss[3];
    q = sq[0] + sq[1] + sq[2] + sq[3];
    float mu  = s * (1.0f / W);
    float var = q * (1.0f / W) - mu * mu;
    float r   = rsqrtf(var + 1e-5f);

    bf16* op = outp + (size_t)row * W;
#pragma unroll
    for (int i = 0; i < NIT; ++i) {
        int idx = tid + i * 256;
        if (idx < W)
            op[idx] = __float2bfloat16((v[i] - mu) * r * scale[idx] + bias[idx]);
    }
}

// ---------------------------------------------------------------------------
// Launcher. WS peak: z 117.4 MB + attn 64.1 MB < proven 191 MB.
// ---------------------------------------------------------------------------
extern "C" void kernel_launch(void* const* d_in, const int* in_sizes, int n_in,
                              void* d_out, int out_size, void* d_ws, size_t ws_size,
                              hipStream_t stream)
{
    const float* x          = (const float*)d_in[0];
    const float* enc_base_w = (const float*)d_in[1];
    const float* enc_A_w    = (const float*)d_in[2];
    const float* enc_B      = (const float*)d_in[3];
    const float* enc_beta   = (const float*)d_in[4];
    const float* Wqkv       = (const float*)d_in[5];
    const float* ln_attn_s  = (const float*)d_in[6];
    const float* ln_attn_b  = (const float*)d_in[7];
    const float* ln_mix_s   = (const float*)d_in[8];
    const float* ln_mix_b   = (const float*)d_in[9];
    const float* w1         = (const float*)d_in[10];
    const float* b1         = (const float*)d_in[11];
    const float* w2         = (const float*)d_in[12];
    const float* b2         = (const float*)d_in[13];
    const float* dec_ln_s   = (const float*)d_in[14];
    const float* dec_ln_b   = (const float*)d_in[15];
    const float* dec_down   = (const float*)d_in[16];
    const float* dec_up     = (const float*)d_in[17];
    const int*   phase_p    = (const int*)d_in[18];
    float* out = (float*)d_out;

    float* ws = (float*)d_ws;
    float* z  = ws;                                  // 8192*3584 fp32 (persistent)
    float* R  = ws + (size_t)BT * ND;                // reusable (<=73.4 MB proven)

    // Wt persists through encoder+attention phases (first 294,912 floats of R)
    bf16*  Wt   = (bf16*)R;                          // 12*384*128 bf16
    float* Rb   = R + 294912;
    // encoder phase (after Wt)
    float* hbuf = Rb;                                // 8192*64 fp32
    bf16*  xb   = (bf16*)(Rb + 524288);              // 8192*1024 bf16
    bf16*  wbb  = xb + (size_t)BT * IO;              // 896*1024 bf16
    // attention phase (after Wt)
    bf16*  xh_b = (bf16*)Rb;                         // 48*1024*128
    bf16*  qkvb = xh_b + (size_t)48 * 1024 * 128;    // 48*1024*384
    bf16*  Vtg  = qkvb + (size_t)48 * 1024 * 384;    // 48*128*1024
    // mixer phase (overwrites all of R)
    bf16* w1b  = (bf16*)R;                           // 3584*896
    bf16* w2b  = w1b + (size_t)HID * DD;             // 896*3584
    bf16* hm   = w2b + (size_t)DD * HID;             // 4096*896  (chunk)
    bf16* gbuf = hm + (size_t)4096 * DD;             // 4096*3584 (chunk)
    // dec phase
    float* t1   = R;                                 // 8192*64 fp32

    // --- one-time conversions
    cvt_wqkv_kernel<<<dim3(2304), 256, 0, stream>>>(Wqkv, Wt);
    cvt_bf16_kernel<<<dim3(8192), 256, 0, stream>>>(x, xb, BT * IO / 4);
    cvt_bf16_kernel<<<dim3(896), 256, 0, stream>>>(enc_base_w, wbb, DD * IO / 4);

    // --- Encoder
    gemm_kernel<64, 64, 16, 4, 4, false, 0>
        <<<dim3(1, 128), 256, 0, stream>>>(x, enc_A_w, hbuf, RK, IO, nullptr);
    gemm_bf16_kernel<3><<<dim3(7, 64), 256, 0, stream>>>(xb, wbb, z, nullptr,
                                                         DD, IO, nullptr);
    gemm_kernel<128, 128, 16, 8, 8, true, 5>
        <<<dim3(28, 64), 256, 0, stream>>>(hbuf, enc_B, z, ND, RK, enc_beta);

    // --- Attention in 2 groups of 48 heads (4 batches each)
    for (int g = 0; g < 2; ++g) {
        ln_attn_kernel<<<dim3(12288), 256, 0, stream>>>(z, xh_b, ln_attn_s, ln_attn_b,
                                                        phase_p, g * 4096);
        qkv_bf16_kernel<<<dim3(3, 8, 48), 256, 0, stream>>>(xh_b, Wt, qkvb, Vtg,
                                                            phase_p, g * 48);
        flash_bf16_kernel<<<dim3(8, 48), 256, 0, stream>>>(qkvb, Vtg, z,
                                                           phase_p, g * 48);
    }

    // --- Mixer MLP on bf16 MFMA, 8 row-chunks of 4096 (of 32768 x 896)
    cvt_bf16_kernel<<<dim3(3136), 256, 0, stream>>>(w1, w1b, HID * DD / 4);
    cvt_bf16_kernel<<<dim3(3136), 256, 0, stream>>>(w2, w2b, DD * HID / 4);
    for (int c = 0; c < 8; ++c) {
        float* zc = z + (size_t)c * 4096 * DD;
        ln_row_bf16_kernel<<<dim3(4096), 256, 0, stream>>>(zc, hm, ln_mix_s, ln_mix_b);
        gemm_bf16_kernel<1><<<dim3(28, 32), 256, 0, stream>>>(hm, w1b, nullptr, gbuf,
                                                              HID, DD, b1);
        gemm_bf16_kernel<2><<<dim3(7, 32), 256, 0, stream>>>(gbuf, w2b, zc, nullptr,
                                                             DD, HID, b2);
    }

    // --- Decoder (fp32): LN in place, then low-rank down/up
    ln_row_kernel<3584><<<dim3(8192), 256, 0, stream>>>(z, z, dec_ln_s, dec_ln_b);
    gemm_kernel<64, 64, 16, 4, 4, false, 0>
        <<<dim3(1, 128), 256, 0, stream>>>(z, dec_down, t1, RK, ND, nullptr);
    gemm_kernel<128, 128, 16, 8, 8, false, 0>
        <<<dim3(8, 64), 256, 0, stream>>>(t1, dec_up, out, IO, RK, nullptr);
}

// Round 5
// 1661.390 us; speedup vs baseline: 6.2606x; 1.3804x over previous
//
#include <hip/hip_runtime.h>
#include <hip/hip_bf16.h>
#include <math.h>

// ---------------------------------------------------------------------------
// Morpher forward. All large GEMMs on bf16 MFMA; encoder low-rank folded into
// a single packed weight; decoder low-rank fp32 split-K.
// Shapes: B=8 T=1024 (BT=8192), N=4, K=3, S=7, DH=128, D=896, ND=3584,
// IO=1024, RANK=64, HIDDEN=3584.
// Phase tables (device-side, phase read from d_in[18]):
//   slot[k]  = {0, 1+(ph&1), 3+(ph&3)}
//   PERM[ph][k][n]: k==0 -> n ; k==1 -> (n+2*(ph&1))&3 ; k==2 -> (n+(ph&3))&3
// ---------------------------------------------------------------------------

#define BT   8192
#define DH   128
#define DD   896
#define ND   3584
#define IO   1024
#define RK   64
#define HID  3584

typedef __attribute__((ext_vector_type(8))) short short8;
typedef __attribute__((ext_vector_type(4))) float f32x4;
typedef __hip_bfloat16 bf16;

// ---------------------------------------------------------------------------
// fp32 tiled GEMM (decoder up-projection only). C = A @ B^T, B is (N x Kd) rm.
// ---------------------------------------------------------------------------
template<int BM, int BN, int BK, int TM, int TN>
__global__ __launch_bounds__(256) void gemm_kernel(const float* __restrict__ A,
                                                   const float* __restrict__ B,
                                                   float* __restrict__ C,
                                                   int N, int Kd)
{
    constexpr int THREADS = (BM / TM) * (BN / TN);
    constexpr int LDA = BM + 4;
    constexpr int LDB = BN + 4;
    __shared__ float As[BK][LDA];
    __shared__ float Bs[BK][LDB];

    const int tid = threadIdx.x;
    constexpr int NX = BN / TN;
    const int tx = tid % NX;
    const int ty = tid / NX;
    const int row0 = blockIdx.y * BM;
    const int col0 = blockIdx.x * BN;

    float acc[TM][TN];
#pragma unroll
    for (int i = 0; i < TM; ++i)
#pragma unroll
        for (int j = 0; j < TN; ++j) acc[i][j] = 0.f;

    for (int k0 = 0; k0 < Kd; k0 += BK) {
        constexpr int AF4 = BM * BK / 4;
        for (int f = tid; f < AF4; f += THREADS) {
            int r  = f / (BK / 4);
            int c4 = (f % (BK / 4)) * 4;
            float4 v = *(const float4*)(A + (size_t)(row0 + r) * Kd + k0 + c4);
            As[c4 + 0][r] = v.x; As[c4 + 1][r] = v.y;
            As[c4 + 2][r] = v.z; As[c4 + 3][r] = v.w;
        }
        constexpr int BF4 = BN * BK / 4;
        for (int f = tid; f < BF4; f += THREADS) {
            int r  = f / (BK / 4);
            int c4 = (f % (BK / 4)) * 4;
            float4 v = *(const float4*)(B + (size_t)(col0 + r) * Kd + k0 + c4);
            Bs[c4 + 0][r] = v.x; Bs[c4 + 1][r] = v.y;
            Bs[c4 + 2][r] = v.z; Bs[c4 + 3][r] = v.w;
        }
        __syncthreads();

#pragma unroll
        for (int kk = 0; kk < BK; ++kk) {
            float a[TM], b[TN];
#pragma unroll
            for (int i = 0; i < TM; i += 4)
                *(float4*)&a[i] = *(const float4*)&As[kk][ty * TM + i];
#pragma unroll
            for (int j = 0; j < TN; j += 4)
                *(float4*)&b[j] = *(const float4*)&Bs[kk][tx * TN + j];
#pragma unroll
            for (int i = 0; i < TM; ++i)
#pragma unroll
                for (int j = 0; j < TN; ++j)
                    acc[i][j] = fmaf(a[i], b[j], acc[i][j]);
        }
        __syncthreads();
    }

    const int crow = row0 + ty * TM;
    const int ccol = col0 + tx * TN;
#pragma unroll
    for (int i = 0; i < TM; ++i) {
        float* cp = C + (size_t)(crow + i) * N + ccol;
#pragma unroll
        for (int j = 0; j < TN; ++j) cp[j] = acc[i][j];
    }
}

// ---------------------------------------------------------------------------
// fp32 split-K skinny GEMM: C(Mx N) += A(M x ld) @ B(N x ld)^T over k-range
// owned by blockIdx.z. 64x64 tile, BK=16, atomicAdd epilogue (C pre-zeroed).
// grid (N/64, M/64, SPLIT)
// ---------------------------------------------------------------------------
template<int SPLIT>
__global__ __launch_bounds__(256) void gemm_splitk_kernel(const float* __restrict__ A,
                                                          const float* __restrict__ B,
                                                          float* __restrict__ C,
                                                          int N, int ld)
{
    __shared__ float As[16][68];
    __shared__ float Bs[16][68];
    const int tid = threadIdx.x;
    const int tx = tid & 15, ty = tid >> 4;
    const int row0 = blockIdx.y * 64;
    const int col0 = blockIdx.x * 64;
    const int kn   = ld / SPLIT;
    const int kbeg = blockIdx.z * kn;

    float acc[4][4];
#pragma unroll
    for (int i = 0; i < 4; ++i)
#pragma unroll
        for (int j = 0; j < 4; ++j) acc[i][j] = 0.f;

    for (int k0 = kbeg; k0 < kbeg + kn; k0 += 16) {
        {
            int r = tid >> 2, c4 = (tid & 3) << 2;
            float4 v = *(const float4*)(A + (size_t)(row0 + r) * ld + k0 + c4);
            As[c4 + 0][r] = v.x; As[c4 + 1][r] = v.y;
            As[c4 + 2][r] = v.z; As[c4 + 3][r] = v.w;
            float4 w = *(const float4*)(B + (size_t)(col0 + r) * ld + k0 + c4);
            Bs[c4 + 0][r] = w.x; Bs[c4 + 1][r] = w.y;
            Bs[c4 + 2][r] = w.z; Bs[c4 + 3][r] = w.w;
        }
        __syncthreads();
#pragma unroll
        for (int kk = 0; kk < 16; ++kk) {
            float a[4], b[4];
            *(float4*)a = *(const float4*)&As[kk][ty * 4];
            *(float4*)b = *(const float4*)&Bs[kk][tx * 4];
#pragma unroll
            for (int i = 0; i < 4; ++i)
#pragma unroll
                for (int j = 0; j < 4; ++j)
                    acc[i][j] = fmaf(a[i], b[j], acc[i][j]);
        }
        __syncthreads();
    }

#pragma unroll
    for (int i = 0; i < 4; ++i)
#pragma unroll
        for (int j = 0; j < 4; ++j)
            atomicAdd(C + (size_t)(row0 + ty * 4 + i) * N + col0 + tx * 4 + j,
                      acc[i][j]);
}

// ---------------------------------------------------------------------------
// bf16 MFMA GEMM: C(MxN) = A(MxK bf16 rm) @ B(NxK bf16 rm)^T
// Block 128x128, 4 waves (2x2), wave 64x64 via 4x4 mfma_f32_16x16x32_bf16.
// BK=64, global_load_lds width-16, unpadded [row][k] LDS.
//  EPI 0: Cf = acc                       (no bias)
//  EPI 1: Cb = bf16(gelu(acc + bias[col]))
//  EPI 2: Cf += acc + bias[col]
// ---------------------------------------------------------------------------
template<int EPI>
__global__ __launch_bounds__(256) void gemm_bf16_kernel(
    const bf16* __restrict__ A,
    const bf16* __restrict__ B,
    float* __restrict__ Cf,
    bf16* __restrict__ Cb,
    int N, int Kd,
    const float* __restrict__ bias)
{
    __shared__ bf16 As[128 * 64];
    __shared__ bf16 Bs[128 * 64];

    const int tid  = threadIdx.x;
    const int wave = tid >> 6;
    const int lane = tid & 63;
    const int wm = wave >> 1, wn = wave & 1;
    const int row0 = blockIdx.y * 128;
    const int col0 = blockIdx.x * 128;
    const int lr = lane & 15;
    const int lq = lane >> 4;
    const int srow = lane >> 3;
    const int scol = (lane & 7) * 8;

    f32x4 acc[4][4];
#pragma unroll
    for (int i = 0; i < 4; ++i)
#pragma unroll
        for (int j = 0; j < 4; ++j) acc[i][j] = (f32x4){0.f, 0.f, 0.f, 0.f};

    for (int k0 = 0; k0 < Kd; k0 += 64) {
#pragma unroll
        for (int j = 0; j < 4; ++j) {
            const int rg = wave * 32 + j * 8;
            __builtin_amdgcn_global_load_lds(
                (const __attribute__((address_space(1))) unsigned int*)
                    (A + (size_t)(row0 + rg + srow) * Kd + k0 + scol),
                (__attribute__((address_space(3))) unsigned int*)(As + rg * 64),
                16, 0, 0);
        }
#pragma unroll
        for (int j = 0; j < 4; ++j) {
            const int rg = wave * 32 + j * 8;
            __builtin_amdgcn_global_load_lds(
                (const __attribute__((address_space(1))) unsigned int*)
                    (B + (size_t)(col0 + rg + srow) * Kd + k0 + scol),
                (__attribute__((address_space(3))) unsigned int*)(Bs + rg * 64),
                16, 0, 0);
        }
        __syncthreads();

#pragma unroll
        for (int s = 0; s < 64; s += 32) {
            short8 af[4], bf[4];
#pragma unroll
            for (int mt = 0; mt < 4; ++mt)
                af[mt] = *(const short8*)&As[(wm * 64 + mt * 16 + lr) * 64 + s + lq * 8];
#pragma unroll
            for (int nt = 0; nt < 4; ++nt)
                bf[nt] = *(const short8*)&Bs[(wn * 64 + nt * 16 + lr) * 64 + s + lq * 8];
#pragma unroll
            for (int mt = 0; mt < 4; ++mt)
#pragma unroll
                for (int nt = 0; nt < 4; ++nt)
                    acc[mt][nt] = __builtin_amdgcn_mfma_f32_16x16x32_bf16(
                        af[mt], bf[nt], acc[mt][nt], 0, 0, 0);
        }
        __syncthreads();
    }

#pragma unroll
    for (int mt = 0; mt < 4; ++mt) {
#pragma unroll
        for (int nt = 0; nt < 4; ++nt) {
            const int col = col0 + wn * 64 + nt * 16 + lr;
            const float bcol = (EPI == 0) ? 0.f : bias[col];
#pragma unroll
            for (int r = 0; r < 4; ++r) {
                const int row = row0 + wm * 64 + mt * 16 + lq * 4 + r;
                float v = acc[mt][nt][r] + bcol;
                if (EPI == 1) {
                    v = 0.5f * v * (1.0f + erff(v * 0.70710678118654752f));
                    Cb[(size_t)row * N + col] = __float2bfloat16(v);
                } else if (EPI == 2) {
                    Cf[(size_t)row * N + col] += v;
                } else {
                    Cf[(size_t)row * N + col] = v;
                }
            }
        }
    }
}

// ---------------------------------------------------------------------------
// Encoder weight fold: W_enc[e,k] = enc_base_w[e%896, k]
//                                 + beta * sum_r enc_B[r, e] * enc_A_w[r, k]
// out bf16 (3584 x 1024). grid (16, 56), 64x64 tile, K=64.
// ---------------------------------------------------------------------------
__global__ __launch_bounds__(256) void pack_enc_kernel(const float* __restrict__ baseW,
                                                       const float* __restrict__ Aw,
                                                       const float* __restrict__ Bv,
                                                       const float* __restrict__ betap,
                                                       bf16* __restrict__ outp)
{
    __shared__ float Ps[64][68];
    __shared__ float Qs[64][68];
    const int tid = threadIdx.x;
    const int e0 = blockIdx.y * 64;
    const int k0 = blockIdx.x * 64;

    for (int f = tid; f < 1024; f += 256) {
        int r = f >> 4, c4 = (f & 15) << 2;
        *(float4*)&Ps[r][c4] = *(const float4*)(Bv + (size_t)r * ND + e0 + c4);
        *(float4*)&Qs[r][c4] = *(const float4*)(Aw + (size_t)r * IO + k0 + c4);
    }
    __syncthreads();

    const int tx = tid & 15, ty = tid >> 4;
    float acc[4][4];
#pragma unroll
    for (int i = 0; i < 4; ++i)
#pragma unroll
        for (int j = 0; j < 4; ++j) acc[i][j] = 0.f;

#pragma unroll 8
    for (int r = 0; r < 64; ++r) {
        float a[4], b[4];
        *(float4*)a = *(const float4*)&Ps[r][ty * 4];
        *(float4*)b = *(const float4*)&Qs[r][tx * 4];
#pragma unroll
        for (int i = 0; i < 4; ++i)
#pragma unroll
            for (int j = 0; j < 4; ++j) acc[i][j] = fmaf(a[i], b[j], acc[i][j]);
    }

    const float beta = betap[0];
#pragma unroll
    for (int i = 0; i < 4; ++i) {
        const int e = e0 + ty * 4 + i;
        const int d = e % DD;
#pragma unroll
        for (int j = 0; j < 4; ++j) {
            const int k = k0 + tx * 4 + j;
            float v = baseW[(size_t)d * IO + k] + beta * acc[i][j];
            outp[(size_t)e * IO + k] = __float2bfloat16(v);
        }
    }
}

// ---------------------------------------------------------------------------
// QKV bf16 MFMA + transposed V emission. grid (3, 8, GQ)
// ---------------------------------------------------------------------------
__global__ __launch_bounds__(256) void qkv_bf16_kernel(
    const bf16* __restrict__ xh,
    const bf16* __restrict__ Wt,
    bf16* __restrict__ qkvb,
    bf16* __restrict__ Vtg,
    const int* __restrict__ phase_p,
    int go)
{
    __shared__ bf16 As[128 * 64];
    __shared__ bf16 Bs[128 * 64];

    const int ph  = phase_p[0] & 3;
    const int zbl = blockIdx.z;
    const int hh  = (go + zbl) % 12;
    const int n   = hh / 3;
    const int k   = hh % 3;
    const int m   = (k == 0) ? n
                  : (k == 1) ? ((n + 2 * (ph & 1)) & 3)
                             : ((n + (ph & 3)) & 3);
    const bf16* A  = xh + (size_t)zbl * (1024 * 128);
    const bf16* Bw = Wt + (size_t)(k * 4 + m) * (384 * 128);

    const int tid  = threadIdx.x;
    const int wave = tid >> 6;
    const int lane = tid & 63;
    const int wm = wave >> 1, wn = wave & 1;
    const int row0 = blockIdx.y * 128;
    const int col0 = blockIdx.x * 128;
    const int lr = lane & 15;
    const int lq = lane >> 4;
    const int srow = lane >> 3;
    const int scol = (lane & 7) * 8;

    f32x4 acc[4][4];
#pragma unroll
    for (int i = 0; i < 4; ++i)
#pragma unroll
        for (int j = 0; j < 4; ++j) acc[i][j] = (f32x4){0.f, 0.f, 0.f, 0.f};

#pragma unroll
    for (int k0 = 0; k0 < 128; k0 += 64) {
#pragma unroll
        for (int j = 0; j < 4; ++j) {
            const int rg = wave * 32 + j * 8;
            __builtin_amdgcn_global_load_lds(
                (const __attribute__((address_space(1))) unsigned int*)
                    (A + (size_t)(row0 + rg + srow) * 128 + k0 + scol),
                (__attribute__((address_space(3))) unsigned int*)(As + rg * 64),
                16, 0, 0);
        }
#pragma unroll
        for (int j = 0; j < 4; ++j) {
            const int rg = wave * 32 + j * 8;
            __builtin_amdgcn_global_load_lds(
                (const __attribute__((address_space(1))) unsigned int*)
                    (Bw + (size_t)(col0 + rg + srow) * 128 + k0 + scol),
                (__attribute__((address_space(3))) unsigned int*)(Bs + rg * 64),
                16, 0, 0);
        }
        __syncthreads();

#pragma unroll
        for (int s = 0; s < 64; s += 32) {
            short8 af[4], bf[4];
#pragma unroll
            for (int mt = 0; mt < 4; ++mt)
                af[mt] = *(const short8*)&As[(wm * 64 + mt * 16 + lr) * 64 + s + lq * 8];
#pragma unroll
            for (int nt = 0; nt < 4; ++nt)
                bf[nt] = *(const short8*)&Bs[(wn * 64 + nt * 16 + lr) * 64 + s + lq * 8];
#pragma unroll
            for (int mt = 0; mt < 4; ++mt)
#pragma unroll
                for (int nt = 0; nt < 4; ++nt)
                    acc[mt][nt] = __builtin_amdgcn_mfma_f32_16x16x32_bf16(
                        af[mt], bf[nt], acc[mt][nt], 0, 0, 0);
        }
        __syncthreads();
    }

    if (col0 < 256) {
        bf16* C = qkvb + (size_t)zbl * (1024 * 384);
#pragma unroll
        for (int mt = 0; mt < 4; ++mt)
#pragma unroll
            for (int nt = 0; nt < 4; ++nt) {
                const int col = col0 + wn * 64 + nt * 16 + lr;
#pragma unroll
                for (int r = 0; r < 4; ++r) {
                    const int row = row0 + wm * 64 + mt * 16 + lq * 4 + r;
                    C[(size_t)row * 384 + col] = __float2bfloat16(acc[mt][nt][r]);
                }
            }
    } else {
        bf16* Vt = Vtg + (size_t)zbl * (128 * 1024);
#pragma unroll
        for (int mt = 0; mt < 4; ++mt)
#pragma unroll
            for (int nt = 0; nt < 4; ++nt) {
                const int d = col0 - 256 + wn * 64 + nt * 16 + lr;
                const int rowb = row0 + wm * 64 + mt * 16 + lq * 4;
                union { bf16 h[4]; uint2 u; } pk;
#pragma unroll
                for (int r = 0; r < 4; ++r)
                    pk.h[r] = __float2bfloat16(acc[mt][nt][r]);
                *(uint2*)(Vt + (size_t)d * 1024 + rowb) = pk.u;
            }
    }
}

// ---------------------------------------------------------------------------
// Flash attention bf16 MFMA: grid (8 q-tiles, GQ heads), 256 threads.
// ---------------------------------------------------------------------------
__global__ __launch_bounds__(256) void flash_bf16_kernel(
    const bf16* __restrict__ qkvb,
    const bf16* __restrict__ Vtg,
    float* __restrict__ z,
    const int* __restrict__ phase_p,
    int go)
{
    __shared__ bf16 Qs[128 * 128];
    __shared__ bf16 KVs[64 * 128];
    __shared__ bf16 Ps[128 * 64];

    const int ph  = phase_p[0] & 3;
    const int zbl = blockIdx.y;
    const int zb  = go + zbl;
    const int b   = zb / 12;
    const int hh  = zb % 12;
    const int n   = hh / 3;
    const int ks  = hh % 3;
    const int slot = (ks == 0) ? 0 : (ks == 1 ? 1 + (ph & 1) : 3 + (ph & 3));
    const int q0  = blockIdx.x * 128;

    const bf16* Qp = qkvb + (size_t)zbl * (1024 * 384);
    const bf16* Kp = Qp + 128;
    const bf16* Vp = Vtg + (size_t)zbl * (128 * 1024);

    const int tid  = threadIdx.x;
    const int wave = tid >> 6;
    const int lane = tid & 63;
    const int lr = lane & 15;
    const int lq = lane >> 4;
    const int sr4 = lane >> 4, sc4 = (lane & 15) * 8;
    const int sr8 = lane >> 3, sc8 = (lane & 7) * 8;

#pragma unroll
    for (int j = 0; j < 8; ++j) {
        const int rg = wave * 32 + j * 4;
        __builtin_amdgcn_global_load_lds(
            (const __attribute__((address_space(1))) unsigned int*)
                (Qp + (size_t)(q0 + rg + sr4) * 384 + sc4),
            (__attribute__((address_space(3))) unsigned int*)(Qs + rg * 128),
            16, 0, 0);
    }

    f32x4 accO[2][8];
    float m_i[2][4], l_i[2][4];
#pragma unroll
    for (int mt = 0; mt < 2; ++mt) {
#pragma unroll
        for (int j = 0; j < 8; ++j) accO[mt][j] = (f32x4){0.f, 0.f, 0.f, 0.f};
#pragma unroll
        for (int r = 0; r < 4; ++r) { m_i[mt][r] = -1e30f; l_i[mt][r] = 0.f; }
    }
    const float sc = 0.08838834764831845f;

    const int jend = q0 + 64;
    for (int j0 = 0; j0 <= jend; j0 += 64) {
#pragma unroll
        for (int j = 0; j < 4; ++j) {
            const int rg = wave * 16 + j * 4;
            __builtin_amdgcn_global_load_lds(
                (const __attribute__((address_space(1))) unsigned int*)
                    (Kp + (size_t)(j0 + rg + sr4) * 384 + sc4),
                (__attribute__((address_space(3))) unsigned int*)(KVs + rg * 128),
                16, 0, 0);
        }
        __syncthreads();

        f32x4 accS[2][4];
#pragma unroll
        for (int mt = 0; mt < 2; ++mt)
#pragma unroll
            for (int nt = 0; nt < 4; ++nt) accS[mt][nt] = (f32x4){0.f, 0.f, 0.f, 0.f};
#pragma unroll
        for (int s = 0; s < 128; s += 32) {
            short8 aq[2], bk[4];
#pragma unroll
            for (int mt = 0; mt < 2; ++mt)
                aq[mt] = *(const short8*)&Qs[(wave * 32 + mt * 16 + lr) * 128 + s + lq * 8];
#pragma unroll
            for (int nt = 0; nt < 4; ++nt)
                bk[nt] = *(const short8*)&KVs[(nt * 16 + lr) * 128 + s + lq * 8];
#pragma unroll
            for (int mt = 0; mt < 2; ++mt)
#pragma unroll
                for (int nt = 0; nt < 4; ++nt)
                    accS[mt][nt] = __builtin_amdgcn_mfma_f32_16x16x32_bf16(
                        aq[mt], bk[nt], accS[mt][nt], 0, 0, 0);
        }

        const bool need_mask = (j0 + 63 > q0);
#pragma unroll
        for (int mt = 0; mt < 2; ++mt) {
#pragma unroll
            for (int r = 0; r < 4; ++r) {
                const int row = q0 + wave * 32 + mt * 16 + lq * 4 + r;
                float sv[4];
#pragma unroll
                for (int nt = 0; nt < 4; ++nt) {
                    float v = accS[mt][nt][r] * sc;
                    if (need_mask && (j0 + nt * 16 + lr > row)) v = -1e30f;
                    sv[nt] = v;
                }
                float mx = fmaxf(fmaxf(sv[0], sv[1]), fmaxf(sv[2], sv[3]));
#pragma unroll
                for (int msk = 8; msk; msk >>= 1) mx = fmaxf(mx, __shfl_xor(mx, msk, 16));
                float mnew = fmaxf(m_i[mt][r], mx);
                float al   = __expf(m_i[mt][r] - mnew);
                float rs = 0.f;
#pragma unroll
                for (int nt = 0; nt < 4; ++nt) {
                    sv[nt] = __expf(sv[nt] - mnew);
                    rs += sv[nt];
                }
#pragma unroll
                for (int msk = 8; msk; msk >>= 1) rs += __shfl_xor(rs, msk, 16);
                l_i[mt][r] = l_i[mt][r] * al + rs;
                m_i[mt][r] = mnew;
#pragma unroll
                for (int d8 = 0; d8 < 8; ++d8) accO[mt][d8][r] *= al;
                const int prow = wave * 32 + mt * 16 + lq * 4 + r;
#pragma unroll
                for (int nt = 0; nt < 4; ++nt)
                    Ps[prow * 64 + nt * 16 + lr] = __float2bfloat16(sv[nt]);
            }
        }
        __syncthreads();

#pragma unroll
        for (int j = 0; j < 4; ++j) {
            const int rg = wave * 32 + j * 8;
            __builtin_amdgcn_global_load_lds(
                (const __attribute__((address_space(1))) unsigned int*)
                    (Vp + (size_t)(rg + sr8) * 1024 + j0 + sc8),
                (__attribute__((address_space(3))) unsigned int*)(KVs + rg * 64),
                16, 0, 0);
        }
        __syncthreads();

#pragma unroll
        for (int kvs = 0; kvs < 64; kvs += 32) {
            short8 ap[2], bv[8];
#pragma unroll
            for (int mt = 0; mt < 2; ++mt)
                ap[mt] = *(const short8*)&Ps[(wave * 32 + mt * 16 + lr) * 64 + kvs + lq * 8];
#pragma unroll
            for (int d8 = 0; d8 < 8; ++d8)
                bv[d8] = *(const short8*)&KVs[(d8 * 16 + lr) * 64 + kvs + lq * 8];
#pragma unroll
            for (int mt = 0; mt < 2; ++mt)
#pragma unroll
                for (int d8 = 0; d8 < 8; ++d8)
                    accO[mt][d8] = __builtin_amdgcn_mfma_f32_16x16x32_bf16(
                        ap[mt], bv[d8], accO[mt][d8], 0, 0, 0);
        }
        __syncthreads();
    }

#pragma unroll
    for (int mt = 0; mt < 2; ++mt) {
#pragma unroll
        for (int r = 0; r < 4; ++r) {
            const int t = q0 + wave * 32 + mt * 16 + lq * 4 + r;
            const float inv = 1.0f / l_i[mt][r];
            float* dst = z + (size_t)(b * 1024 + t) * ND + n * DD + slot * DH;
#pragma unroll
            for (int d8 = 0; d8 < 8; ++d8)
                dst[d8 * 16 + lr] += accO[mt][d8][r] * inv;
        }
    }
}

// ---------------------------------------------------------------------------
// fp32 -> bf16 elementwise (n4 = n/4)
// ---------------------------------------------------------------------------
__global__ __launch_bounds__(256) void cvt_bf16_kernel(const float* __restrict__ src,
                                                       bf16* __restrict__ dst,
                                                       int n4)
{
    int i = blockIdx.x * 256 + threadIdx.x;
    if (i < n4) {
        float4 v = ((const float4*)src)[i];
        bf16* d = dst + (size_t)i * 4;
        d[0] = __float2bfloat16(v.x);
        d[1] = __float2bfloat16(v.y);
        d[2] = __float2bfloat16(v.z);
        d[3] = __float2bfloat16(v.w);
    }
}

// Wqkv (12,128,384) fp32 -> Wt (12,384,128) bf16
__global__ __launch_bounds__(256) void cvt_wqkv_kernel(const float* __restrict__ W,
                                                       bf16* __restrict__ Wt)
{
    int o = blockIdx.x * 256 + threadIdx.x;
    if (o < 12 * 384 * 128) {
        int i = o / 49152, rem = o % 49152;
        int e = rem / 128, d = rem % 128;
        Wt[o] = __float2bfloat16(W[(size_t)i * 49152 + d * 384 + e]);
    }
}

// ---------------------------------------------------------------------------
// Attention-input LayerNorm -> bf16 head-major xh. grid = GQ*256 blocks.
// ---------------------------------------------------------------------------
__global__ __launch_bounds__(256) void ln_attn_kernel(const float* __restrict__ z,
                                                      bf16* __restrict__ xh,
                                                      const float* __restrict__ scale,
                                                      const float* __restrict__ bias,
                                                      const int* __restrict__ phase_p,
                                                      int bt0)
{
    const int ph   = phase_p[0] & 3;
    const int lane = threadIdx.x & 63;
    const int row  = blockIdx.x * 4 + (threadIdx.x >> 6);
    const int k    = row % 3;
    const int n    = (row / 3) & 3;
    const int btl  = row / 12;
    const int slot = (k == 0) ? 0 : (k == 1 ? 1 + (ph & 1) : 3 + (ph & 3));
    const int bt   = bt0 + btl;

    const float* src = z + (size_t)bt * ND + n * DD + slot * DH + lane * 2;
    float2 v = *(const float2*)src;
    float s = v.x + v.y;
    float q = v.x * v.x + v.y * v.y;
#pragma unroll
    for (int m = 32; m; m >>= 1) { s += __shfl_xor(s, m); q += __shfl_xor(q, m); }
    float mu  = s * (1.0f / 128.0f);
    float var = q * (1.0f / 128.0f) - mu * mu;
    float r   = rsqrtf(var + 1e-5f);

    float2 sc2 = *(const float2*)(scale + lane * 2);
    float2 bi2 = *(const float2*)(bias + lane * 2);
    const int bl = btl >> 10, t = btl & 1023;
    union { bf16 h[2]; unsigned int u; } pk;
    pk.h[0] = __float2bfloat16((v.x - mu) * r * sc2.x + bi2.x);
    pk.h[1] = __float2bfloat16((v.y - mu) * r * sc2.y + bi2.y);
    *(unsigned int*)(xh + (size_t)((bl * 12 + n * 3 + k) * 1024 + t) * DH + lane * 2) = pk.u;
}

// ---------------------------------------------------------------------------
// Row LayerNorm fp32 out (W=3584 decoder), safe in-place.
// ---------------------------------------------------------------------------
template<int W>
__global__ __launch_bounds__(256) void ln_row_kernel(const float* __restrict__ in,
                                                     float* __restrict__ outp,
                                                     const float* __restrict__ scale,
                                                     const float* __restrict__ bias)
{
    constexpr int NIT = (W + 255) / 256;
    const int row = blockIdx.x;
    const int tid = threadIdx.x;
    const float* rp = in + (size_t)row * W;

    float v[NIT];
    float s = 0.f, q = 0.f;
#pragma unroll
    for (int i = 0; i < NIT; ++i) {
        int idx = tid + i * 256;
        if (idx < W) { float t = rp[idx]; v[i] = t; s += t; q += t * t; }
        else v[i] = 0.f;
    }
#pragma unroll
    for (int m = 32; m; m >>= 1) { s += __shfl_xor(s, m); q += __shfl_xor(q, m); }
    __shared__ float ss[4], sq[4];
    if ((tid & 63) == 0) { ss[tid >> 6] = s; sq[tid >> 6] = q; }
    __syncthreads();
    s = ss[0] + ss[1] + ss[2] + ss[3];
    q = sq[0] + sq[1] + sq[2] + sq[3];
    float mu  = s * (1.0f / W);
    float var = q * (1.0f / W) - mu * mu;
    float r   = rsqrtf(var + 1e-5f);

    float* op = outp + (size_t)row * W;
#pragma unroll
    for (int i = 0; i < NIT; ++i) {
        int idx = tid + i * 256;
        if (idx < W) op[idx] = (v[i] - mu) * r * scale[idx] + bias[idx];
    }
}

// ---------------------------------------------------------------------------
// Row LayerNorm, W=896, bf16 output (mixer input).
// ---------------------------------------------------------------------------
__global__ __launch_bounds__(256) void ln_row_bf16_kernel(const float* __restrict__ in,
                                                          bf16* __restrict__ outp,
                                                          const float* __restrict__ scale,
                                                          const float* __restrict__ bias)
{
    constexpr int W = 896, NIT = 4;
    const int row = blockIdx.x;
    const int tid = threadIdx.x;
    const float* rp = in + (size_t)row * W;

    float v[NIT];
    float s = 0.f, q = 0.f;
#pragma unroll
    for (int i = 0; i < NIT; ++i) {
        int idx = tid + i * 256;
        if (idx < W) { float t = rp[idx]; v[i] = t; s += t; q += t * t; }
        else v[i] = 0.f;
    }
#pragma unroll
    for (int m = 32; m; m >>= 1) { s += __shfl_xor(s, m); q += __shfl_xor(q, m); }
    __shared__ float ss[4], sq[4];
    if ((tid & 63) == 0) { ss[tid >> 6] = s; sq[tid >> 6] = q; }
    __syncthreads();
    s = ss[0] + ss[1] + ss[2] + ss[3];
    q = sq[0] + sq[1] + sq[2] + sq[3];
    float mu  = s * (1.0f / W);
    float var = q * (1.0f / W) - mu * mu;
    float r   = rsqrtf(var + 1e-5f);

    bf16* op = outp + (size_t)row * W;
#pragma unroll
    for (int i = 0; i < NIT; ++i) {
        int idx = tid + i * 256;
        if (idx < W)
            op[idx] = __float2bfloat16((v[i] - mu) * r * scale[idx] + bias[idx]);
    }
}

// ---------------------------------------------------------------------------
// Launcher. ws-aware layout:
//   base: z 117.4 MB persistent + R region.
//   attn: 1 group (127.0 MB in R) if ws >= 246 MB else 2 groups (64.1 MB).
//   mixer: chunk 8192 (86.2 MB in R) if ws >= 205 MB else 4096 (49.5 MB).
// ---------------------------------------------------------------------------
extern "C" void kernel_launch(void* const* d_in, const int* in_sizes, int n_in,
                              void* d_out, int out_size, void* d_ws, size_t ws_size,
                              hipStream_t stream)
{
    const float* x          = (const float*)d_in[0];
    const float* enc_base_w = (const float*)d_in[1];
    const float* enc_A_w    = (const float*)d_in[2];
    const float* enc_B      = (const float*)d_in[3];
    const float* enc_beta   = (const float*)d_in[4];
    const float* Wqkv       = (const float*)d_in[5];
    const float* ln_attn_s  = (const float*)d_in[6];
    const float* ln_attn_b  = (const float*)d_in[7];
    const float* ln_mix_s   = (const float*)d_in[8];
    const float* ln_mix_b   = (const float*)d_in[9];
    const float* w1         = (const float*)d_in[10];
    const float* b1         = (const float*)d_in[11];
    const float* w2         = (const float*)d_in[12];
    const float* b2         = (const float*)d_in[13];
    const float* dec_ln_s   = (const float*)d_in[14];
    const float* dec_ln_b   = (const float*)d_in[15];
    const float* dec_down   = (const float*)d_in[16];
    const float* dec_up     = (const float*)d_in[17];
    const int*   phase_p    = (const int*)d_in[18];
    float* out = (float*)d_out;

    float* ws = (float*)d_ws;
    float* z  = ws;                                  // 8192*3584 fp32 (persistent)
    float* R  = ws + (size_t)BT * ND;

    const int GQ = (ws_size >= 246000000UL) ? 96 : 48;   // attn heads per group
    const int CH = (ws_size >= 205000000UL) ? 8192 : 4096; // mixer chunk rows

    // encoder phase
    bf16* xb   = (bf16*)R;                           // 8192*1024
    bf16* Wenc = xb + (size_t)BT * IO;               // 3584*1024
    // attention phase
    bf16* Wt   = (bf16*)R;                           // 12*384*128
    bf16* xh_b = Wt + 12 * 384 * 128;                // GQ*1024*128
    bf16* qkvb = xh_b + (size_t)GQ * 1024 * 128;     // GQ*1024*384
    bf16* Vtg  = qkvb + (size_t)GQ * 1024 * 384;     // GQ*128*1024
    // mixer phase
    bf16* w1b  = (bf16*)R;                           // 3584*896
    bf16* w2b  = w1b + (size_t)HID * DD;             // 896*3584
    bf16* hm   = w2b + (size_t)DD * HID;             // CH*896
    bf16* gbuf = hm + (size_t)CH * DD;               // CH*3584
    // dec phase
    float* t1  = R;                                  // 8192*64 fp32

    // --- Encoder: fold low-rank into W_enc, then one bf16 GEMM into z
    cvt_bf16_kernel<<<dim3(8192), 256, 0, stream>>>(x, xb, BT * IO / 4);
    pack_enc_kernel<<<dim3(16, 56), 256, 0, stream>>>(enc_base_w, enc_A_w, enc_B,
                                                      enc_beta, Wenc);
    gemm_bf16_kernel<0><<<dim3(28, 64), 256, 0, stream>>>(xb, Wenc, z, nullptr,
                                                          ND, IO, nullptr);

    // --- Attention (bf16 MFMA), GQ heads per group
    cvt_wqkv_kernel<<<dim3(2304), 256, 0, stream>>>(Wqkv, Wt);
    const int ngroups = 96 / GQ;
    for (int g = 0; g < ngroups; ++g) {
        ln_attn_kernel<<<dim3(GQ * 256), 256, 0, stream>>>(z, xh_b, ln_attn_s,
                                                           ln_attn_b, phase_p,
                                                           g * (GQ / 12) * 1024);
        qkv_bf16_kernel<<<dim3(3, 8, GQ), 256, 0, stream>>>(xh_b, Wt, qkvb, Vtg,
                                                            phase_p, g * GQ);
        flash_bf16_kernel<<<dim3(8, GQ), 256, 0, stream>>>(qkvb, Vtg, z,
                                                           phase_p, g * GQ);
    }

    // --- Mixer MLP on bf16 MFMA, chunks of CH rows (of 32768 x 896)
    cvt_bf16_kernel<<<dim3(3136), 256, 0, stream>>>(w1, w1b, HID * DD / 4);
    cvt_bf16_kernel<<<dim3(3136), 256, 0, stream>>>(w2, w2b, DD * HID / 4);
    for (int c = 0; c < 32768 / CH; ++c) {
        float* zc = z + (size_t)c * CH * DD;
        ln_row_bf16_kernel<<<dim3(CH), 256, 0, stream>>>(zc, hm, ln_mix_s, ln_mix_b);
        gemm_bf16_kernel<1><<<dim3(28, CH / 128), 256, 0, stream>>>(hm, w1b, nullptr,
                                                                    gbuf, HID, DD, b1);
        gemm_bf16_kernel<2><<<dim3(7, CH / 128), 256, 0, stream>>>(gbuf, w2b, zc,
                                                                   nullptr, DD, HID, b2);
    }

    // --- Decoder: LN in place, split-K down-projection, up-projection
    ln_row_kernel<3584><<<dim3(8192), 256, 0, stream>>>(z, z, dec_ln_s, dec_ln_b);
    hipMemsetAsync(t1, 0, (size_t)BT * RK * sizeof(float), stream);
    gemm_splitk_kernel<8><<<dim3(1, 128, 8), 256, 0, stream>>>(z, dec_down, t1,
                                                               RK, ND);
    gemm_kernel<128, 128, 16, 8, 8>
        <<<dim3(8, 64), 256, 0, stream>>>(t1, dec_up, out, IO, RK);
}

// Round 6
// 1562.381 us; speedup vs baseline: 6.6574x; 1.0634x over previous
//
#include <hip/hip_runtime.h>
#include <hip/hip_bf16.h>
#include <math.h>

// ---------------------------------------------------------------------------
// Morpher forward. All large GEMMs bf16 MFMA; encoder low-rank folded;
// decoder low-rank fp32 split-K; flash attention Q-in-registers BQ=64.
// Shapes: B=8 T=1024 (BT=8192), N=4, K=3, S=7, DH=128, D=896, ND=3584,
// IO=1024, RANK=64, HIDDEN=3584.
// Phase tables (device): slot[k] = {0, 1+(ph&1), 3+(ph&3)};
// PERM[ph][k][n]: k==0 -> n ; k==1 -> (n+2*(ph&1))&3 ; k==2 -> (n+(ph&3))&3
// ---------------------------------------------------------------------------

#define BT   8192
#define DH   128
#define DD   896
#define ND   3584
#define IO   1024
#define RK   64
#define HID  3584

typedef __attribute__((ext_vector_type(8))) short short8;
typedef __attribute__((ext_vector_type(4))) float f32x4;
typedef __hip_bfloat16 bf16;

// ---------------------------------------------------------------------------
// fp32 tiled GEMM (decoder up-projection only). C = A @ B^T, B (N x Kd) rm.
// ---------------------------------------------------------------------------
template<int BM, int BN, int BK, int TM, int TN>
__global__ __launch_bounds__(256) void gemm_kernel(const float* __restrict__ A,
                                                   const float* __restrict__ B,
                                                   float* __restrict__ C,
                                                   int N, int Kd)
{
    constexpr int THREADS = (BM / TM) * (BN / TN);
    constexpr int LDA = BM + 4;
    constexpr int LDB = BN + 4;
    __shared__ float As[BK][LDA];
    __shared__ float Bs[BK][LDB];

    const int tid = threadIdx.x;
    constexpr int NX = BN / TN;
    const int tx = tid % NX;
    const int ty = tid / NX;
    const int row0 = blockIdx.y * BM;
    const int col0 = blockIdx.x * BN;

    float acc[TM][TN];
#pragma unroll
    for (int i = 0; i < TM; ++i)
#pragma unroll
        for (int j = 0; j < TN; ++j) acc[i][j] = 0.f;

    for (int k0 = 0; k0 < Kd; k0 += BK) {
        constexpr int AF4 = BM * BK / 4;
        for (int f = tid; f < AF4; f += THREADS) {
            int r  = f / (BK / 4);
            int c4 = (f % (BK / 4)) * 4;
            float4 v = *(const float4*)(A + (size_t)(row0 + r) * Kd + k0 + c4);
            As[c4 + 0][r] = v.x; As[c4 + 1][r] = v.y;
            As[c4 + 2][r] = v.z; As[c4 + 3][r] = v.w;
        }
        constexpr int BF4 = BN * BK / 4;
        for (int f = tid; f < BF4; f += THREADS) {
            int r  = f / (BK / 4);
            int c4 = (f % (BK / 4)) * 4;
            float4 v = *(const float4*)(B + (size_t)(col0 + r) * Kd + k0 + c4);
            Bs[c4 + 0][r] = v.x; Bs[c4 + 1][r] = v.y;
            Bs[c4 + 2][r] = v.z; Bs[c4 + 3][r] = v.w;
        }
        __syncthreads();

#pragma unroll
        for (int kk = 0; kk < BK; ++kk) {
            float a[TM], b[TN];
#pragma unroll
            for (int i = 0; i < TM; i += 4)
                *(float4*)&a[i] = *(const float4*)&As[kk][ty * TM + i];
#pragma unroll
            for (int j = 0; j < TN; j += 4)
                *(float4*)&b[j] = *(const float4*)&Bs[kk][tx * TN + j];
#pragma unroll
            for (int i = 0; i < TM; ++i)
#pragma unroll
                for (int j = 0; j < TN; ++j)
                    acc[i][j] = fmaf(a[i], b[j], acc[i][j]);
        }
        __syncthreads();
    }

    const int crow = row0 + ty * TM;
    const int ccol = col0 + tx * TN;
#pragma unroll
    for (int i = 0; i < TM; ++i) {
        float* cp = C + (size_t)(crow + i) * N + ccol;
#pragma unroll
        for (int j = 0; j < TN; ++j) cp[j] = acc[i][j];
    }
}

// ---------------------------------------------------------------------------
// fp32 split-K skinny GEMM (decoder down-projection): 64x64 tile, BK=16,
// atomicAdd epilogue (C pre-zeroed). grid (N/64, M/64, SPLIT)
// ---------------------------------------------------------------------------
template<int SPLIT>
__global__ __launch_bounds__(256) void gemm_splitk_kernel(const float* __restrict__ A,
                                                          const float* __restrict__ B,
                                                          float* __restrict__ C,
                                                          int N, int ld)
{
    __shared__ float As[16][68];
    __shared__ float Bs[16][68];
    const int tid = threadIdx.x;
    const int tx = tid & 15, ty = tid >> 4;
    const int row0 = blockIdx.y * 64;
    const int col0 = blockIdx.x * 64;
    const int kn   = ld / SPLIT;
    const int kbeg = blockIdx.z * kn;

    float acc[4][4];
#pragma unroll
    for (int i = 0; i < 4; ++i)
#pragma unroll
        for (int j = 0; j < 4; ++j) acc[i][j] = 0.f;

    for (int k0 = kbeg; k0 < kbeg + kn; k0 += 16) {
        {
            int r = tid >> 2, c4 = (tid & 3) << 2;
            float4 v = *(const float4*)(A + (size_t)(row0 + r) * ld + k0 + c4);
            As[c4 + 0][r] = v.x; As[c4 + 1][r] = v.y;
            As[c4 + 2][r] = v.z; As[c4 + 3][r] = v.w;
            float4 w = *(const float4*)(B + (size_t)(col0 + r) * ld + k0 + c4);
            Bs[c4 + 0][r] = w.x; Bs[c4 + 1][r] = w.y;
            Bs[c4 + 2][r] = w.z; Bs[c4 + 3][r] = w.w;
        }
        __syncthreads();
#pragma unroll
        for (int kk = 0; kk < 16; ++kk) {
            float a[4], b[4];
            *(float4*)a = *(const float4*)&As[kk][ty * 4];
            *(float4*)b = *(const float4*)&Bs[kk][tx * 4];
#pragma unroll
            for (int i = 0; i < 4; ++i)
#pragma unroll
                for (int j = 0; j < 4; ++j)
                    acc[i][j] = fmaf(a[i], b[j], acc[i][j]);
        }
        __syncthreads();
    }

#pragma unroll
    for (int i = 0; i < 4; ++i)
#pragma unroll
        for (int j = 0; j < 4; ++j)
            atomicAdd(C + (size_t)(row0 + ty * 4 + i) * N + col0 + tx * 4 + j,
                      acc[i][j]);
}

// ---------------------------------------------------------------------------
// bf16 MFMA GEMM: C(MxN) = A(M x ld bf16 rm) @ B(N x ld bf16 rm)^T over
// k-range [blockIdx.z*Kit, +Kit). Block 128x128, 4 waves, BK=64,
// global_load_lds width-16, unpadded [row][k] LDS.
//  EPI 0: Cf = acc
//  EPI 1: Cb = bf16(gelu(acc + bias[col]))
//  EPI 4: atomicAdd(Cf, acc + (blockIdx.z==0 ? bias[col] : 0))
// ---------------------------------------------------------------------------
template<int EPI>
__global__ __launch_bounds__(256) void gemm_bf16_kernel(
    const bf16* __restrict__ A,
    const bf16* __restrict__ B,
    float* __restrict__ Cf,
    bf16* __restrict__ Cb,
    int N, int Kit, int ld,
    const float* __restrict__ bias)
{
    __shared__ bf16 As[128 * 64];
    __shared__ bf16 Bs[128 * 64];

    const int tid  = threadIdx.x;
    const int wave = tid >> 6;
    const int lane = tid & 63;
    const int wm = wave >> 1, wn = wave & 1;
    const int row0 = blockIdx.y * 128;
    const int col0 = blockIdx.x * 128;
    const int lr = lane & 15;
    const int lq = lane >> 4;
    const int srow = lane >> 3;
    const int scol = (lane & 7) * 8;
    const int kbeg = blockIdx.z * Kit;

    f32x4 acc[4][4];
#pragma unroll
    for (int i = 0; i < 4; ++i)
#pragma unroll
        for (int j = 0; j < 4; ++j) acc[i][j] = (f32x4){0.f, 0.f, 0.f, 0.f};

    for (int k0 = kbeg; k0 < kbeg + Kit; k0 += 64) {
#pragma unroll
        for (int j = 0; j < 4; ++j) {
            const int rg = wave * 32 + j * 8;
            __builtin_amdgcn_global_load_lds(
                (const __attribute__((address_space(1))) unsigned int*)
                    (A + (size_t)(row0 + rg + srow) * ld + k0 + scol),
                (__attribute__((address_space(3))) unsigned int*)(As + rg * 64),
                16, 0, 0);
        }
#pragma unroll
        for (int j = 0; j < 4; ++j) {
            const int rg = wave * 32 + j * 8;
            __builtin_amdgcn_global_load_lds(
                (const __attribute__((address_space(1))) unsigned int*)
                    (B + (size_t)(col0 + rg + srow) * ld + k0 + scol),
                (__attribute__((address_space(3))) unsigned int*)(Bs + rg * 64),
                16, 0, 0);
        }
        __syncthreads();

#pragma unroll
        for (int s = 0; s < 64; s += 32) {
            short8 af[4], bf[4];
#pragma unroll
            for (int mt = 0; mt < 4; ++mt)
                af[mt] = *(const short8*)&As[(wm * 64 + mt * 16 + lr) * 64 + s + lq * 8];
#pragma unroll
            for (int nt = 0; nt < 4; ++nt)
                bf[nt] = *(const short8*)&Bs[(wn * 64 + nt * 16 + lr) * 64 + s + lq * 8];
#pragma unroll
            for (int mt = 0; mt < 4; ++mt)
#pragma unroll
                for (int nt = 0; nt < 4; ++nt)
                    acc[mt][nt] = __builtin_amdgcn_mfma_f32_16x16x32_bf16(
                        af[mt], bf[nt], acc[mt][nt], 0, 0, 0);
        }
        __syncthreads();
    }

#pragma unroll
    for (int mt = 0; mt < 4; ++mt) {
#pragma unroll
        for (int nt = 0; nt < 4; ++nt) {
            const int col = col0 + wn * 64 + nt * 16 + lr;
            float bcol = 0.f;
            if (EPI == 1) bcol = bias[col];
            if (EPI == 4 && blockIdx.z == 0) bcol = bias[col];
#pragma unroll
            for (int r = 0; r < 4; ++r) {
                const int row = row0 + wm * 64 + mt * 16 + lq * 4 + r;
                float v = acc[mt][nt][r] + bcol;
                if (EPI == 1) {
                    v = 0.5f * v * (1.0f + erff(v * 0.70710678118654752f));
                    Cb[(size_t)row * N + col] = __float2bfloat16(v);
                } else if (EPI == 4) {
                    atomicAdd(Cf + (size_t)row * N + col, v);
                } else {
                    Cf[(size_t)row * N + col] = v;
                }
            }
        }
    }
}

// ---------------------------------------------------------------------------
// Encoder weight fold: W_enc[e,k] = enc_base_w[e%896,k] + beta*(B^T A)[e,k]
// out bf16 (3584 x 1024). grid (16, 56).
// ---------------------------------------------------------------------------
__global__ __launch_bounds__(256) void pack_enc_kernel(const float* __restrict__ baseW,
                                                       const float* __restrict__ Aw,
                                                       const float* __restrict__ Bv,
                                                       const float* __restrict__ betap,
                                                       bf16* __restrict__ outp)
{
    __shared__ float Ps[64][68];
    __shared__ float Qs[64][68];
    const int tid = threadIdx.x;
    const int e0 = blockIdx.y * 64;
    const int k0 = blockIdx.x * 64;

    for (int f = tid; f < 1024; f += 256) {
        int r = f >> 4, c4 = (f & 15) << 2;
        *(float4*)&Ps[r][c4] = *(const float4*)(Bv + (size_t)r * ND + e0 + c4);
        *(float4*)&Qs[r][c4] = *(const float4*)(Aw + (size_t)r * IO + k0 + c4);
    }
    __syncthreads();

    const int tx = tid & 15, ty = tid >> 4;
    float acc[4][4];
#pragma unroll
    for (int i = 0; i < 4; ++i)
#pragma unroll
        for (int j = 0; j < 4; ++j) acc[i][j] = 0.f;

#pragma unroll 8
    for (int r = 0; r < 64; ++r) {
        float a[4], b[4];
        *(float4*)a = *(const float4*)&Ps[r][ty * 4];
        *(float4*)b = *(const float4*)&Qs[r][tx * 4];
#pragma unroll
        for (int i = 0; i < 4; ++i)
#pragma unroll
            for (int j = 0; j < 4; ++j) acc[i][j] = fmaf(a[i], b[j], acc[i][j]);
    }

    const float beta = betap[0];
#pragma unroll
    for (int i = 0; i < 4; ++i) {
        const int e = e0 + ty * 4 + i;
        const int d = e % DD;
#pragma unroll
        for (int j = 0; j < 4; ++j) {
            const int k = k0 + tx * 4 + j;
            float v = baseW[(size_t)d * IO + k] + beta * acc[i][j];
            outp[(size_t)e * IO + k] = __float2bfloat16(v);
        }
    }
}

// ---------------------------------------------------------------------------
// QKV bf16 MFMA -> separate Q (t,d), K (t,d), V^T (d,t). grid (3, 8, GQ)
// ---------------------------------------------------------------------------
__global__ __launch_bounds__(256) void qkv_bf16_kernel(
    const bf16* __restrict__ xh,
    const bf16* __restrict__ Wt,
    bf16* __restrict__ Qg,
    bf16* __restrict__ Kg,
    bf16* __restrict__ Vtg,
    const int* __restrict__ phase_p,
    int go)
{
    __shared__ bf16 As[128 * 64];
    __shared__ bf16 Bs[128 * 64];

    const int ph  = phase_p[0] & 3;
    const int zbl = blockIdx.z;
    const int hh  = (go + zbl) % 12;
    const int n   = hh / 3;
    const int k   = hh % 3;
    const int m   = (k == 0) ? n
                  : (k == 1) ? ((n + 2 * (ph & 1)) & 3)
                             : ((n + (ph & 3)) & 3);
    const bf16* A  = xh + (size_t)zbl * (1024 * 128);
    const bf16* Bw = Wt + (size_t)(k * 4 + m) * (384 * 128);

    const int tid  = threadIdx.x;
    const int wave = tid >> 6;
    const int lane = tid & 63;
    const int wm = wave >> 1, wn = wave & 1;
    const int row0 = blockIdx.y * 128;
    const int col0 = blockIdx.x * 128;
    const int lr = lane & 15;
    const int lq = lane >> 4;
    const int srow = lane >> 3;
    const int scol = (lane & 7) * 8;

    f32x4 acc[4][4];
#pragma unroll
    for (int i = 0; i < 4; ++i)
#pragma unroll
        for (int j = 0; j < 4; ++j) acc[i][j] = (f32x4){0.f, 0.f, 0.f, 0.f};

#pragma unroll
    for (int k0 = 0; k0 < 128; k0 += 64) {
#pragma unroll
        for (int j = 0; j < 4; ++j) {
            const int rg = wave * 32 + j * 8;
            __builtin_amdgcn_global_load_lds(
                (const __attribute__((address_space(1))) unsigned int*)
                    (A + (size_t)(row0 + rg + srow) * 128 + k0 + scol),
                (__attribute__((address_space(3))) unsigned int*)(As + rg * 64),
                16, 0, 0);
        }
#pragma unroll
        for (int j = 0; j < 4; ++j) {
            const int rg = wave * 32 + j * 8;
            __builtin_amdgcn_global_load_lds(
                (const __attribute__((address_space(1))) unsigned int*)
                    (Bw + (size_t)(col0 + rg + srow) * 128 + k0 + scol),
                (__attribute__((address_space(3))) unsigned int*)(Bs + rg * 64),
                16, 0, 0);
        }
        __syncthreads();

#pragma unroll
        for (int s = 0; s < 64; s += 32) {
            short8 af[4], bf[4];
#pragma unroll
            for (int mt = 0; mt < 4; ++mt)
                af[mt] = *(const short8*)&As[(wm * 64 + mt * 16 + lr) * 64 + s + lq * 8];
#pragma unroll
            for (int nt = 0; nt < 4; ++nt)
                bf[nt] = *(const short8*)&Bs[(wn * 64 + nt * 16 + lr) * 64 + s + lq * 8];
#pragma unroll
            for (int mt = 0; mt < 4; ++mt)
#pragma unroll
                for (int nt = 0; nt < 4; ++nt)
                    acc[mt][nt] = __builtin_amdgcn_mfma_f32_16x16x32_bf16(
                        af[mt], bf[nt], acc[mt][nt], 0, 0, 0);
        }
        __syncthreads();
    }

    if (col0 < 256) {
        bf16* C = (col0 == 0 ? Qg : Kg) + (size_t)zbl * (1024 * 128);
#pragma unroll
        for (int mt = 0; mt < 4; ++mt)
#pragma unroll
            for (int nt = 0; nt < 4; ++nt) {
                const int col = wn * 64 + nt * 16 + lr;   // local 0..127
#pragma unroll
                for (int r = 0; r < 4; ++r) {
                    const int row = row0 + wm * 64 + mt * 16 + lq * 4 + r;
                    C[(size_t)row * 128 + col] = __float2bfloat16(acc[mt][nt][r]);
                }
            }
    } else {
        bf16* Vt = Vtg + (size_t)zbl * (128 * 1024);
#pragma unroll
        for (int mt = 0; mt < 4; ++mt)
#pragma unroll
            for (int nt = 0; nt < 4; ++nt) {
                const int d = wn * 64 + nt * 16 + lr;
                const int rowb = row0 + wm * 64 + mt * 16 + lq * 4;
                union { bf16 h[4]; uint2 u; } pk;
#pragma unroll
                for (int r = 0; r < 4; ++r)
                    pk.h[r] = __float2bfloat16(acc[mt][nt][r]);
                *(uint2*)(Vt + (size_t)d * 1024 + rowb) = pk.u;
            }
    }
}

// ---------------------------------------------------------------------------
// Flash attention bf16 MFMA, Q in registers. grid (GQ heads, 16 q-tiles).
// BQ=64 (wave: 16 rows), BKV=64. LDS: Ks 16K + Vs 16K + Ps 8K = 40 KB.
// Ps is wave-private -> 2 barriers per kv-tile.
// ---------------------------------------------------------------------------
__global__ __launch_bounds__(256) void flash_bf16_kernel(
    const bf16* __restrict__ Qg,
    const bf16* __restrict__ Kg,
    const bf16* __restrict__ Vtg,
    float* __restrict__ z,
    const int* __restrict__ phase_p,
    int go)
{
    __shared__ bf16 Ks[64 * 128];
    __shared__ bf16 Vs[128 * 64];
    __shared__ bf16 Ps[64 * 64];

    const int ph  = phase_p[0] & 3;
    const int zbl = blockIdx.x;
    const int zb  = go + zbl;
    const int b   = zb / 12;
    const int hh  = zb % 12;
    const int n   = hh / 3;
    const int ks  = hh % 3;
    const int slot = (ks == 0) ? 0 : (ks == 1 ? 1 + (ph & 1) : 3 + (ph & 3));
    const int q0  = blockIdx.y * 64;

    const bf16* Qp = Qg  + (size_t)zbl * (1024 * 128);
    const bf16* Kp = Kg  + (size_t)zbl * (1024 * 128);
    const bf16* Vp = Vtg + (size_t)zbl * (128 * 1024);

    const int tid  = threadIdx.x;
    const int wave = tid >> 6;
    const int lane = tid & 63;
    const int lr = lane & 15;
    const int lq = lane >> 4;
    const int sr4 = lane >> 4, sc4 = (lane & 15) * 8;   // 256B-row staging
    const int sr8 = lane >> 3, sc8 = (lane & 7) * 8;    // 128B-row staging

    // Q rows q0 + wave*16 + lr, A-frag layout (cols s*32 + lq*8)
    short8 qreg[4];
#pragma unroll
    for (int s = 0; s < 4; ++s)
        qreg[s] = *(const short8*)(Qp + (size_t)(q0 + wave * 16 + lr) * 128
                                   + s * 32 + lq * 8);

    f32x4 accO[8];
    float m_i[4], l_i[4];
#pragma unroll
    for (int j = 0; j < 8; ++j) accO[j] = (f32x4){0.f, 0.f, 0.f, 0.f};
#pragma unroll
    for (int r = 0; r < 4; ++r) { m_i[r] = -1e30f; l_i[r] = 0.f; }
    const float sc = 0.08838834764831845f;   // 1/sqrt(128)

    for (int j0 = 0; j0 <= q0; j0 += 64) {
        // stage K [64][128] and V^T [128][64] concurrently
#pragma unroll
        for (int j = 0; j < 4; ++j) {
            const int rg = wave * 16 + j * 4;
            __builtin_amdgcn_global_load_lds(
                (const __attribute__((address_space(1))) unsigned int*)
                    (Kp + (size_t)(j0 + rg + sr4) * 128 + sc4),
                (__attribute__((address_space(3))) unsigned int*)(Ks + rg * 128),
                16, 0, 0);
        }
#pragma unroll
        for (int j = 0; j < 4; ++j) {
            const int rg = wave * 32 + j * 8;
            __builtin_amdgcn_global_load_lds(
                (const __attribute__((address_space(1))) unsigned int*)
                    (Vp + (size_t)(rg + sr8) * 1024 + j0 + sc8),
                (__attribute__((address_space(3))) unsigned int*)(Vs + rg * 64),
                16, 0, 0);
        }
        __syncthreads();

        // S = Q K^T (wave: 16 q x 64 kv)
        f32x4 accS[4];
#pragma unroll
        for (int nt = 0; nt < 4; ++nt) accS[nt] = (f32x4){0.f, 0.f, 0.f, 0.f};
#pragma unroll
        for (int s = 0; s < 4; ++s) {
            short8 bk[4];
#pragma unroll
            for (int nt = 0; nt < 4; ++nt)
                bk[nt] = *(const short8*)&Ks[(nt * 16 + lr) * 128 + s * 32 + lq * 8];
#pragma unroll
            for (int nt = 0; nt < 4; ++nt)
                accS[nt] = __builtin_amdgcn_mfma_f32_16x16x32_bf16(
                    qreg[s], bk[nt], accS[nt], 0, 0, 0);
        }

        // online softmax (rows q0 + wave*16 + lq*4 + r)
        const bool need_mask = (j0 == q0);
#pragma unroll
        for (int r = 0; r < 4; ++r) {
            const int row = q0 + wave * 16 + lq * 4 + r;
            float sv[4];
#pragma unroll
            for (int nt = 0; nt < 4; ++nt) {
                float v = accS[nt][r] * sc;
                if (need_mask && (j0 + nt * 16 + lr > row)) v = -1e30f;
                sv[nt] = v;
            }
            float mx = fmaxf(fmaxf(sv[0], sv[1]), fmaxf(sv[2], sv[3]));
#pragma unroll
            for (int msk = 8; msk; msk >>= 1) mx = fmaxf(mx, __shfl_xor(mx, msk, 16));
            float mnew = fmaxf(m_i[r], mx);
            float al   = __expf(m_i[r] - mnew);
            float rs = 0.f;
#pragma unroll
            for (int nt = 0; nt < 4; ++nt) {
                sv[nt] = __expf(sv[nt] - mnew);
                rs += sv[nt];
            }
#pragma unroll
            for (int msk = 8; msk; msk >>= 1) rs += __shfl_xor(rs, msk, 16);
            l_i[r] = l_i[r] * al + rs;
            m_i[r] = mnew;
#pragma unroll
            for (int d8 = 0; d8 < 8; ++d8) accO[d8][r] *= al;
            const int prow = wave * 16 + lq * 4 + r;
#pragma unroll
            for (int nt = 0; nt < 4; ++nt)
                Ps[prow * 64 + nt * 16 + lr] = __float2bfloat16(sv[nt]);
        }
        // Ps is wave-private: no barrier needed before PV

        // O += P V (wave: 16 q x 128 d)
#pragma unroll
        for (int kvs = 0; kvs < 64; kvs += 32) {
            short8 ap = *(const short8*)&Ps[(wave * 16 + lr) * 64 + kvs + lq * 8];
            short8 bv[8];
#pragma unroll
            for (int d8 = 0; d8 < 8; ++d8)
                bv[d8] = *(const short8*)&Vs[(d8 * 16 + lr) * 64 + kvs + lq * 8];
#pragma unroll
            for (int d8 = 0; d8 < 8; ++d8)
                accO[d8] = __builtin_amdgcn_mfma_f32_16x16x32_bf16(
                    ap, bv[d8], accO[d8], 0, 0, 0);
        }
        __syncthreads();   // Ks/Vs reads done before next staging
    }

    // epilogue: z += O / l at head slot
#pragma unroll
    for (int r = 0; r < 4; ++r) {
        const int t = q0 + wave * 16 + lq * 4 + r;
        const float inv = 1.0f / l_i[r];
        float* dst = z + (size_t)(b * 1024 + t) * ND + n * DD + slot * DH;
#pragma unroll
        for (int d8 = 0; d8 < 8; ++d8)
            dst[d8 * 16 + lr] += accO[d8][r] * inv;
    }
}

// ---------------------------------------------------------------------------
// fp32 -> bf16 elementwise (n4 = n/4)
// ---------------------------------------------------------------------------
__global__ __launch_bounds__(256) void cvt_bf16_kernel(const float* __restrict__ src,
                                                       bf16* __restrict__ dst,
                                                       int n4)
{
    int i = blockIdx.x * 256 + threadIdx.x;
    if (i < n4) {
        float4 v = ((const float4*)src)[i];
        bf16* d = dst + (size_t)i * 4;
        d[0] = __float2bfloat16(v.x);
        d[1] = __float2bfloat16(v.y);
        d[2] = __float2bfloat16(v.z);
        d[3] = __float2bfloat16(v.w);
    }
}

// Wqkv (12,128,384) fp32 -> Wt (12,384,128) bf16
__global__ __launch_bounds__(256) void cvt_wqkv_kernel(const float* __restrict__ W,
                                                       bf16* __restrict__ Wt)
{
    int o = blockIdx.x * 256 + threadIdx.x;
    if (o < 12 * 384 * 128) {
        int i = o / 49152, rem = o % 49152;
        int e = rem / 128, d = rem % 128;
        Wt[o] = __float2bfloat16(W[(size_t)i * 49152 + d * 384 + e]);
    }
}

// ---------------------------------------------------------------------------
// Attention-input LayerNorm -> bf16 head-major xh. grid = GQ*256 blocks.
// ---------------------------------------------------------------------------
__global__ __launch_bounds__(256) void ln_attn_kernel(const float* __restrict__ z,
                                                      bf16* __restrict__ xh,
                                                      const float* __restrict__ scale,
                                                      const float* __restrict__ bias,
                                                      const int* __restrict__ phase_p,
                                                      int bt0)
{
    const int ph   = phase_p[0] & 3;
    const int lane = threadIdx.x & 63;
    const int row  = blockIdx.x * 4 + (threadIdx.x >> 6);
    const int k    = row % 3;
    const int n    = (row / 3) & 3;
    const int btl  = row / 12;
    const int slot = (k == 0) ? 0 : (k == 1 ? 1 + (ph & 1) : 3 + (ph & 3));
    const int bt   = bt0 + btl;

    const float* src = z + (size_t)bt * ND + n * DD + slot * DH + lane * 2;
    float2 v = *(const float2*)src;
    float s = v.x + v.y;
    float q = v.x * v.x + v.y * v.y;
#pragma unroll
    for (int m = 32; m; m >>= 1) { s += __shfl_xor(s, m); q += __shfl_xor(q, m); }
    float mu  = s * (1.0f / 128.0f);
    float var = q * (1.0f / 128.0f) - mu * mu;
    float r   = rsqrtf(var + 1e-5f);

    float2 sc2 = *(const float2*)(scale + lane * 2);
    float2 bi2 = *(const float2*)(bias + lane * 2);
    const int bl = btl >> 10, t = btl & 1023;
    union { bf16 h[2]; unsigned int u; } pk;
    pk.h[0] = __float2bfloat16((v.x - mu) * r * sc2.x + bi2.x);
    pk.h[1] = __float2bfloat16((v.y - mu) * r * sc2.y + bi2.y);
    *(unsigned int*)(xh + (size_t)((bl * 12 + n * 3 + k) * 1024 + t) * DH + lane * 2) = pk.u;
}

// ---------------------------------------------------------------------------
// Row LayerNorm fp32 out (W=3584 decoder), safe in-place.
// ---------------------------------------------------------------------------
template<int W>
__global__ __launch_bounds__(256) void ln_row_kernel(const float* __restrict__ in,
                                                     float* __restrict__ outp,
                                                     const float* __restrict__ scale,
                                                     const float* __restrict__ bias)
{
    constexpr int NIT = (W + 255) / 256;
    const int row = blockIdx.x;
    const int tid = threadIdx.x;
    const float* rp = in + (size_t)row * W;

    float v[NIT];
    float s = 0.f, q = 0.f;
#pragma unroll
    for (int i = 0; i < NIT; ++i) {
        int idx = tid + i * 256;
        if (idx < W) { float t = rp[idx]; v[i] = t; s += t; q += t * t; }
        else v[i] = 0.f;
    }
#pragma unroll
    for (int m = 32; m; m >>= 1) { s += __shfl_xor(s, m); q += __shfl_xor(q, m); }
    __shared__ float ss[4], sq[4];
    if ((tid & 63) == 0) { ss[tid >> 6] = s; sq[tid >> 6] = q; }
    __syncthreads();
    s = ss[0] + ss[1] + ss[2] + ss[3];
    q = sq[0] + sq[1] + sq[2] + sq[3];
    float mu  = s * (1.0f / W);
    float var = q * (1.0f / W) - mu * mu;
    float r   = rsqrtf(var + 1e-5f);

    float* op = outp + (size_t)row * W;
#pragma unroll
    for (int i = 0; i < NIT; ++i) {
        int idx = tid + i * 256;
        if (idx < W) op[idx] = (v[i] - mu) * r * scale[idx] + bias[idx];
    }
}

// ---------------------------------------------------------------------------
// Row LayerNorm, W=896, bf16 output (mixer input).
// ---------------------------------------------------------------------------
__global__ __launch_bounds__(256) void ln_row_bf16_kernel(const float* __restrict__ in,
                                                          bf16* __restrict__ outp,
                                                          const float* __restrict__ scale,
                                                          const float* __restrict__ bias)
{
    constexpr int W = 896, NIT = 4;
    const int row = blockIdx.x;
    const int tid = threadIdx.x;
    const float* rp = in + (size_t)row * W;

    float v[NIT];
    float s = 0.f, q = 0.f;
#pragma unroll
    for (int i = 0; i < NIT; ++i) {
        int idx = tid + i * 256;
        if (idx < W) { float t = rp[idx]; v[i] = t; s += t; q += t * t; }
        else v[i] = 0.f;
    }
#pragma unroll
    for (int m = 32; m; m >>= 1) { s += __shfl_xor(s, m); q += __shfl_xor(q, m); }
    __shared__ float ss[4], sq[4];
    if ((tid & 63) == 0) { ss[tid >> 6] = s; sq[tid >> 6] = q; }
    __syncthreads();
    s = ss[0] + ss[1] + ss[2] + ss[3];
    q = sq[0] + sq[1] + sq[2] + sq[3];
    float mu  = s * (1.0f / W);
    float var = q * (1.0f / W) - mu * mu;
    float r   = rsqrtf(var + 1e-5f);

    bf16* op = outp + (size_t)row * W;
#pragma unroll
    for (int i = 0; i < NIT; ++i) {
        int idx = tid + i * 256;
        if (idx < W)
            op[idx] = __float2bfloat16((v[i] - mu) * r * scale[idx] + bias[idx]);
    }
}

// ---------------------------------------------------------------------------
// Launcher. ws-aware:
//   attn: GQ=96 (102 MB in R -> needs ws>=230 MB) else GQ=48 (51.5 MB).
//   mixer: CH=8192 (86.2 MB) if ws>=205 MB else 4096 (49.5 MB).
// ---------------------------------------------------------------------------
extern "C" void kernel_launch(void* const* d_in, const int* in_sizes, int n_in,
                              void* d_out, int out_size, void* d_ws, size_t ws_size,
                              hipStream_t stream)
{
    const float* x          = (const float*)d_in[0];
    const float* enc_base_w = (const float*)d_in[1];
    const float* enc_A_w    = (const float*)d_in[2];
    const float* enc_B      = (const float*)d_in[3];
    const float* enc_beta   = (const float*)d_in[4];
    const float* Wqkv       = (const float*)d_in[5];
    const float* ln_attn_s  = (const float*)d_in[6];
    const float* ln_attn_b  = (const float*)d_in[7];
    const float* ln_mix_s   = (const float*)d_in[8];
    const float* ln_mix_b   = (const float*)d_in[9];
    const float* w1         = (const float*)d_in[10];
    const float* b1         = (const float*)d_in[11];
    const float* w2         = (const float*)d_in[12];
    const float* b2         = (const float*)d_in[13];
    const float* dec_ln_s   = (const float*)d_in[14];
    const float* dec_ln_b   = (const float*)d_in[15];
    const float* dec_down   = (const float*)d_in[16];
    const float* dec_up     = (const float*)d_in[17];
    const int*   phase_p    = (const int*)d_in[18];
    float* out = (float*)d_out;

    float* ws = (float*)d_ws;
    float* z  = ws;                                  // 8192*3584 fp32 (persistent)
    float* R  = ws + (size_t)BT * ND;

    const int GQ = (ws_size >= 230000000UL) ? 96 : 48;
    const int CH = (ws_size >= 205000000UL) ? 8192 : 4096;

    // encoder phase
    bf16* xb   = (bf16*)R;                           // 8192*1024
    bf16* Wenc = xb + (size_t)BT * IO;               // 3584*1024
    // attention phase
    bf16* Wt   = (bf16*)R;                           // 12*384*128
    bf16* xh_b = Wt + 12 * 384 * 128;                // GQ*1024*128
    bf16* Qb   = xh_b + (size_t)GQ * 1024 * 128;     // GQ*1024*128
    bf16* Kb   = Qb + (size_t)GQ * 1024 * 128;       // GQ*1024*128
    bf16* Vtg  = Kb + (size_t)GQ * 1024 * 128;       // GQ*128*1024
    // mixer phase
    bf16* w1b  = (bf16*)R;                           // 3584*896
    bf16* w2b  = w1b + (size_t)HID * DD;             // 896*3584
    bf16* hm   = w2b + (size_t)DD * HID;             // CH*896
    bf16* gbuf = hm + (size_t)CH * DD;               // CH*3584
    // dec phase
    float* t1  = R;                                  // 8192*64 fp32

    // --- Encoder: fold low-rank into W_enc, then one bf16 GEMM into z
    cvt_bf16_kernel<<<dim3(8192), 256, 0, stream>>>(x, xb, BT * IO / 4);
    pack_enc_kernel<<<dim3(16, 56), 256, 0, stream>>>(enc_base_w, enc_A_w, enc_B,
                                                      enc_beta, Wenc);
    gemm_bf16_kernel<0><<<dim3(28, 64), 256, 0, stream>>>(xb, Wenc, z, nullptr,
                                                          ND, IO, IO, nullptr);

    // --- Attention (bf16 MFMA), GQ heads per group
    cvt_wqkv_kernel<<<dim3(2304), 256, 0, stream>>>(Wqkv, Wt);
    const int ngroups = 96 / GQ;
    for (int g = 0; g < ngroups; ++g) {
        ln_attn_kernel<<<dim3(GQ * 256), 256, 0, stream>>>(z, xh_b, ln_attn_s,
                                                           ln_attn_b, phase_p,
                                                           g * (GQ / 12) * 1024);
        qkv_bf16_kernel<<<dim3(3, 8, GQ), 256, 0, stream>>>(xh_b, Wt, Qb, Kb, Vtg,
                                                            phase_p, g * GQ);
        flash_bf16_kernel<<<dim3(GQ, 16), 256, 0, stream>>>(Qb, Kb, Vtg, z,
                                                            phase_p, g * GQ);
    }

    // --- Mixer MLP on bf16 MFMA, chunks of CH rows (of 32768 x 896)
    cvt_bf16_kernel<<<dim3(3136), 256, 0, stream>>>(w1, w1b, HID * DD / 4);
    cvt_bf16_kernel<<<dim3(3136), 256, 0, stream>>>(w2, w2b, DD * HID / 4);
    for (int c = 0; c < 32768 / CH; ++c) {
        float* zc = z + (size_t)c * CH * DD;
        ln_row_bf16_kernel<<<dim3(CH), 256, 0, stream>>>(zc, hm, ln_mix_s, ln_mix_b);
        gemm_bf16_kernel<1><<<dim3(28, CH / 128), 256, 0, stream>>>(
            hm, w1b, nullptr, gbuf, HID, DD, DD, b1);
        gemm_bf16_kernel<4><<<dim3(7, CH / 128, 2), 256, 0, stream>>>(
            gbuf, w2b, zc, nullptr, DD, HID / 2, HID, b2);
    }

    // --- Decoder: LN in place, split-K down-projection, up-projection
    ln_row_kernel<3584><<<dim3(8192), 256, 0, stream>>>(z, z, dec_ln_s, dec_ln_b);
    hipMemsetAsync(t1, 0, (size_t)BT * RK * sizeof(float), stream);
    gemm_splitk_kernel<8><<<dim3(1, 128, 8), 256, 0, stream>>>(z, dec_down, t1,
                                                               RK, ND);
    gemm_kernel<128, 128, 16, 8, 8>
        <<<dim3(8, 64), 256, 0, stream>>>(t1, dec_up, out, IO, RK);
}

// Round 7
// 1417.028 us; speedup vs baseline: 7.3403x; 1.1026x over previous
//
#include <hip/hip_runtime.h>
#include <hip/hip_bf16.h>
#include <math.h>

// ---------------------------------------------------------------------------
// Morpher forward. All large GEMMs bf16 MFMA; encoder low-rank folded;
// decoder low-rank fp32 split-K; flash attention Q-in-registers BQ=64.
// R7: fast A&S erf gelu epilogue; w2 single-dispatch (no atomics).
// Shapes: B=8 T=1024 (BT=8192), N=4, K=3, S=7, DH=128, D=896, ND=3584,
// IO=1024, RANK=64, HIDDEN=3584.
// Phase tables (device): slot[k] = {0, 1+(ph&1), 3+(ph&3)};
// PERM[ph][k][n]: k==0 -> n ; k==1 -> (n+2*(ph&1))&3 ; k==2 -> (n+(ph&3))&3
// ---------------------------------------------------------------------------

#define BT   8192
#define DH   128
#define DD   896
#define ND   3584
#define IO   1024
#define RK   64
#define HID  3584

typedef __attribute__((ext_vector_type(8))) short short8;
typedef __attribute__((ext_vector_type(4))) float f32x4;
typedef __hip_bfloat16 bf16;

// Fast gelu: exact-form 0.5x(1+erf(x/sqrt2)) with A&S 7.1.26 erf
// (max abs err ~1.5e-7; ~15 VALU ops vs ~40 for libm erff).
__device__ __forceinline__ float gelu_f(float v)
{
    float u = v * 0.70710678118654752f;
    float a = fabsf(u);
    float t = __builtin_amdgcn_rcpf(1.0f + 0.3275911f * a);
    float p = t * (0.254829592f + t * (-0.284496736f + t * (1.421413741f +
              t * (-1.453152027f + t * 1.061405429f))));
    float er = 1.0f - p * __expf(-u * u);
    er = copysignf(er, u);
    return 0.5f * v * (1.0f + er);
}

// ---------------------------------------------------------------------------
// fp32 tiled GEMM (decoder up-projection only). C = A @ B^T, B (N x Kd) rm.
// ---------------------------------------------------------------------------
template<int BM, int BN, int BK, int TM, int TN>
__global__ __launch_bounds__(256) void gemm_kernel(const float* __restrict__ A,
                                                   const float* __restrict__ B,
                                                   float* __restrict__ C,
                                                   int N, int Kd)
{
    constexpr int THREADS = (BM / TM) * (BN / TN);
    constexpr int LDA = BM + 4;
    constexpr int LDB = BN + 4;
    __shared__ float As[BK][LDA];
    __shared__ float Bs[BK][LDB];

    const int tid = threadIdx.x;
    constexpr int NX = BN / TN;
    const int tx = tid % NX;
    const int ty = tid / NX;
    const int row0 = blockIdx.y * BM;
    const int col0 = blockIdx.x * BN;

    float acc[TM][TN];
#pragma unroll
    for (int i = 0; i < TM; ++i)
#pragma unroll
        for (int j = 0; j < TN; ++j) acc[i][j] = 0.f;

    for (int k0 = 0; k0 < Kd; k0 += BK) {
        constexpr int AF4 = BM * BK / 4;
        for (int f = tid; f < AF4; f += THREADS) {
            int r  = f / (BK / 4);
            int c4 = (f % (BK / 4)) * 4;
            float4 v = *(const float4*)(A + (size_t)(row0 + r) * Kd + k0 + c4);
            As[c4 + 0][r] = v.x; As[c4 + 1][r] = v.y;
            As[c4 + 2][r] = v.z; As[c4 + 3][r] = v.w;
        }
        constexpr int BF4 = BN * BK / 4;
        for (int f = tid; f < BF4; f += THREADS) {
            int r  = f / (BK / 4);
            int c4 = (f % (BK / 4)) * 4;
            float4 v = *(const float4*)(B + (size_t)(col0 + r) * Kd + k0 + c4);
            Bs[c4 + 0][r] = v.x; Bs[c4 + 1][r] = v.y;
            Bs[c4 + 2][r] = v.z; Bs[c4 + 3][r] = v.w;
        }
        __syncthreads();

#pragma unroll
        for (int kk = 0; kk < BK; ++kk) {
            float a[TM], b[TN];
#pragma unroll
            for (int i = 0; i < TM; i += 4)
                *(float4*)&a[i] = *(const float4*)&As[kk][ty * TM + i];
#pragma unroll
            for (int j = 0; j < TN; j += 4)
                *(float4*)&b[j] = *(const float4*)&Bs[kk][tx * TN + j];
#pragma unroll
            for (int i = 0; i < TM; ++i)
#pragma unroll
                for (int j = 0; j < TN; ++j)
                    acc[i][j] = fmaf(a[i], b[j], acc[i][j]);
        }
        __syncthreads();
    }

    const int crow = row0 + ty * TM;
    const int ccol = col0 + tx * TN;
#pragma unroll
    for (int i = 0; i < TM; ++i) {
        float* cp = C + (size_t)(crow + i) * N + ccol;
#pragma unroll
        for (int j = 0; j < TN; ++j) cp[j] = acc[i][j];
    }
}

// ---------------------------------------------------------------------------
// fp32 split-K skinny GEMM (decoder down-projection): 64x64 tile, BK=16,
// atomicAdd epilogue (C pre-zeroed). grid (N/64, M/64, SPLIT)
// ---------------------------------------------------------------------------
template<int SPLIT>
__global__ __launch_bounds__(256) void gemm_splitk_kernel(const float* __restrict__ A,
                                                          const float* __restrict__ B,
                                                          float* __restrict__ C,
                                                          int N, int ld)
{
    __shared__ float As[16][68];
    __shared__ float Bs[16][68];
    const int tid = threadIdx.x;
    const int tx = tid & 15, ty = tid >> 4;
    const int row0 = blockIdx.y * 64;
    const int col0 = blockIdx.x * 64;
    const int kn   = ld / SPLIT;
    const int kbeg = blockIdx.z * kn;

    float acc[4][4];
#pragma unroll
    for (int i = 0; i < 4; ++i)
#pragma unroll
        for (int j = 0; j < 4; ++j) acc[i][j] = 0.f;

    for (int k0 = kbeg; k0 < kbeg + kn; k0 += 16) {
        {
            int r = tid >> 2, c4 = (tid & 3) << 2;
            float4 v = *(const float4*)(A + (size_t)(row0 + r) * ld + k0 + c4);
            As[c4 + 0][r] = v.x; As[c4 + 1][r] = v.y;
            As[c4 + 2][r] = v.z; As[c4 + 3][r] = v.w;
            float4 w = *(const float4*)(B + (size_t)(col0 + r) * ld + k0 + c4);
            Bs[c4 + 0][r] = w.x; Bs[c4 + 1][r] = w.y;
            Bs[c4 + 2][r] = w.z; Bs[c4 + 3][r] = w.w;
        }
        __syncthreads();
#pragma unroll
        for (int kk = 0; kk < 16; ++kk) {
            float a[4], b[4];
            *(float4*)a = *(const float4*)&As[kk][ty * 4];
            *(float4*)b = *(const float4*)&Bs[kk][tx * 4];
#pragma unroll
            for (int i = 0; i < 4; ++i)
#pragma unroll
                for (int j = 0; j < 4; ++j)
                    acc[i][j] = fmaf(a[i], b[j], acc[i][j]);
        }
        __syncthreads();
    }

#pragma unroll
    for (int i = 0; i < 4; ++i)
#pragma unroll
        for (int j = 0; j < 4; ++j)
            atomicAdd(C + (size_t)(row0 + ty * 4 + i) * N + col0 + tx * 4 + j,
                      acc[i][j]);
}

// ---------------------------------------------------------------------------
// bf16 MFMA GEMM: C(MxN) = A(M x ld bf16 rm) @ B(N x ld bf16 rm)^T.
// Block 128x128, 4 waves, BK=64, global_load_lds width-16, unpadded LDS.
//  EPI 0: Cf = acc
//  EPI 1: Cb = bf16(gelu(acc + bias[col]))   (fast A&S erf)
//  EPI 2: Cf += acc + bias[col]
// ---------------------------------------------------------------------------
template<int EPI>
__global__ __launch_bounds__(256) void gemm_bf16_kernel(
    const bf16* __restrict__ A,
    const bf16* __restrict__ B,
    float* __restrict__ Cf,
    bf16* __restrict__ Cb,
    int N, int Kd,
    const float* __restrict__ bias)
{
    __shared__ bf16 As[128 * 64];
    __shared__ bf16 Bs[128 * 64];

    const int tid  = threadIdx.x;
    const int wave = tid >> 6;
    const int lane = tid & 63;
    const int wm = wave >> 1, wn = wave & 1;
    const int row0 = blockIdx.y * 128;
    const int col0 = blockIdx.x * 128;
    const int lr = lane & 15;
    const int lq = lane >> 4;
    const int srow = lane >> 3;
    const int scol = (lane & 7) * 8;

    f32x4 acc[4][4];
#pragma unroll
    for (int i = 0; i < 4; ++i)
#pragma unroll
        for (int j = 0; j < 4; ++j) acc[i][j] = (f32x4){0.f, 0.f, 0.f, 0.f};

    for (int k0 = 0; k0 < Kd; k0 += 64) {
#pragma unroll
        for (int j = 0; j < 4; ++j) {
            const int rg = wave * 32 + j * 8;
            __builtin_amdgcn_global_load_lds(
                (const __attribute__((address_space(1))) unsigned int*)
                    (A + (size_t)(row0 + rg + srow) * Kd + k0 + scol),
                (__attribute__((address_space(3))) unsigned int*)(As + rg * 64),
                16, 0, 0);
        }
#pragma unroll
        for (int j = 0; j < 4; ++j) {
            const int rg = wave * 32 + j * 8;
            __builtin_amdgcn_global_load_lds(
                (const __attribute__((address_space(1))) unsigned int*)
                    (B + (size_t)(col0 + rg + srow) * Kd + k0 + scol),
                (__attribute__((address_space(3))) unsigned int*)(Bs + rg * 64),
                16, 0, 0);
        }
        __syncthreads();

#pragma unroll
        for (int s = 0; s < 64; s += 32) {
            short8 af[4], bf[4];
#pragma unroll
            for (int mt = 0; mt < 4; ++mt)
                af[mt] = *(const short8*)&As[(wm * 64 + mt * 16 + lr) * 64 + s + lq * 8];
#pragma unroll
            for (int nt = 0; nt < 4; ++nt)
                bf[nt] = *(const short8*)&Bs[(wn * 64 + nt * 16 + lr) * 64 + s + lq * 8];
#pragma unroll
            for (int mt = 0; mt < 4; ++mt)
#pragma unroll
                for (int nt = 0; nt < 4; ++nt)
                    acc[mt][nt] = __builtin_amdgcn_mfma_f32_16x16x32_bf16(
                        af[mt], bf[nt], acc[mt][nt], 0, 0, 0);
        }
        __syncthreads();
    }

#pragma unroll
    for (int mt = 0; mt < 4; ++mt) {
#pragma unroll
        for (int nt = 0; nt < 4; ++nt) {
            const int col = col0 + wn * 64 + nt * 16 + lr;
            const float bcol = (EPI == 0) ? 0.f : bias[col];
#pragma unroll
            for (int r = 0; r < 4; ++r) {
                const int row = row0 + wm * 64 + mt * 16 + lq * 4 + r;
                float v = acc[mt][nt][r] + bcol;
                if (EPI == 1) {
                    Cb[(size_t)row * N + col] = __float2bfloat16(gelu_f(v));
                } else if (EPI == 2) {
                    Cf[(size_t)row * N + col] += v;
                } else {
                    Cf[(size_t)row * N + col] = v;
                }
            }
        }
    }
}

// ---------------------------------------------------------------------------
// Encoder weight fold: W_enc[e,k] = enc_base_w[e%896,k] + beta*(B^T A)[e,k]
// out bf16 (3584 x 1024). grid (16, 56).
// ---------------------------------------------------------------------------
__global__ __launch_bounds__(256) void pack_enc_kernel(const float* __restrict__ baseW,
                                                       const float* __restrict__ Aw,
                                                       const float* __restrict__ Bv,
                                                       const float* __restrict__ betap,
                                                       bf16* __restrict__ outp)
{
    __shared__ float Ps[64][68];
    __shared__ float Qs[64][68];
    const int tid = threadIdx.x;
    const int e0 = blockIdx.y * 64;
    const int k0 = blockIdx.x * 64;

    for (int f = tid; f < 1024; f += 256) {
        int r = f >> 4, c4 = (f & 15) << 2;
        *(float4*)&Ps[r][c4] = *(const float4*)(Bv + (size_t)r * ND + e0 + c4);
        *(float4*)&Qs[r][c4] = *(const float4*)(Aw + (size_t)r * IO + k0 + c4);
    }
    __syncthreads();

    const int tx = tid & 15, ty = tid >> 4;
    float acc[4][4];
#pragma unroll
    for (int i = 0; i < 4; ++i)
#pragma unroll
        for (int j = 0; j < 4; ++j) acc[i][j] = 0.f;

#pragma unroll 8
    for (int r = 0; r < 64; ++r) {
        float a[4], b[4];
        *(float4*)a = *(const float4*)&Ps[r][ty * 4];
        *(float4*)b = *(const float4*)&Qs[r][tx * 4];
#pragma unroll
        for (int i = 0; i < 4; ++i)
#pragma unroll
            for (int j = 0; j < 4; ++j) acc[i][j] = fmaf(a[i], b[j], acc[i][j]);
    }

    const float beta = betap[0];
#pragma unroll
    for (int i = 0; i < 4; ++i) {
        const int e = e0 + ty * 4 + i;
        const int d = e % DD;
#pragma unroll
        for (int j = 0; j < 4; ++j) {
            const int k = k0 + tx * 4 + j;
            float v = baseW[(size_t)d * IO + k] + beta * acc[i][j];
            outp[(size_t)e * IO + k] = __float2bfloat16(v);
        }
    }
}

// ---------------------------------------------------------------------------
// QKV bf16 MFMA -> separate Q (t,d), K (t,d), V^T (d,t). grid (3, 8, GQ)
// ---------------------------------------------------------------------------
__global__ __launch_bounds__(256) void qkv_bf16_kernel(
    const bf16* __restrict__ xh,
    const bf16* __restrict__ Wt,
    bf16* __restrict__ Qg,
    bf16* __restrict__ Kg,
    bf16* __restrict__ Vtg,
    const int* __restrict__ phase_p,
    int go)
{
    __shared__ bf16 As[128 * 64];
    __shared__ bf16 Bs[128 * 64];

    const int ph  = phase_p[0] & 3;
    const int zbl = blockIdx.z;
    const int hh  = (go + zbl) % 12;
    const int n   = hh / 3;
    const int k   = hh % 3;
    const int m   = (k == 0) ? n
                  : (k == 1) ? ((n + 2 * (ph & 1)) & 3)
                             : ((n + (ph & 3)) & 3);
    const bf16* A  = xh + (size_t)zbl * (1024 * 128);
    const bf16* Bw = Wt + (size_t)(k * 4 + m) * (384 * 128);

    const int tid  = threadIdx.x;
    const int wave = tid >> 6;
    const int lane = tid & 63;
    const int wm = wave >> 1, wn = wave & 1;
    const int row0 = blockIdx.y * 128;
    const int col0 = blockIdx.x * 128;
    const int lr = lane & 15;
    const int lq = lane >> 4;
    const int srow = lane >> 3;
    const int scol = (lane & 7) * 8;

    f32x4 acc[4][4];
#pragma unroll
    for (int i = 0; i < 4; ++i)
#pragma unroll
        for (int j = 0; j < 4; ++j) acc[i][j] = (f32x4){0.f, 0.f, 0.f, 0.f};

#pragma unroll
    for (int k0 = 0; k0 < 128; k0 += 64) {
#pragma unroll
        for (int j = 0; j < 4; ++j) {
            const int rg = wave * 32 + j * 8;
            __builtin_amdgcn_global_load_lds(
                (const __attribute__((address_space(1))) unsigned int*)
                    (A + (size_t)(row0 + rg + srow) * 128 + k0 + scol),
                (__attribute__((address_space(3))) unsigned int*)(As + rg * 64),
                16, 0, 0);
        }
#pragma unroll
        for (int j = 0; j < 4; ++j) {
            const int rg = wave * 32 + j * 8;
            __builtin_amdgcn_global_load_lds(
                (const __attribute__((address_space(1))) unsigned int*)
                    (Bw + (size_t)(col0 + rg + srow) * 128 + k0 + scol),
                (__attribute__((address_space(3))) unsigned int*)(Bs + rg * 64),
                16, 0, 0);
        }
        __syncthreads();

#pragma unroll
        for (int s = 0; s < 64; s += 32) {
            short8 af[4], bf[4];
#pragma unroll
            for (int mt = 0; mt < 4; ++mt)
                af[mt] = *(const short8*)&As[(wm * 64 + mt * 16 + lr) * 64 + s + lq * 8];
#pragma unroll
            for (int nt = 0; nt < 4; ++nt)
                bf[nt] = *(const short8*)&Bs[(wn * 64 + nt * 16 + lr) * 64 + s + lq * 8];
#pragma unroll
            for (int mt = 0; mt < 4; ++mt)
#pragma unroll
                for (int nt = 0; nt < 4; ++nt)
                    acc[mt][nt] = __builtin_amdgcn_mfma_f32_16x16x32_bf16(
                        af[mt], bf[nt], acc[mt][nt], 0, 0, 0);
        }
        __syncthreads();
    }

    if (col0 < 256) {
        bf16* C = (col0 == 0 ? Qg : Kg) + (size_t)zbl * (1024 * 128);
#pragma unroll
        for (int mt = 0; mt < 4; ++mt)
#pragma unroll
            for (int nt = 0; nt < 4; ++nt) {
                const int col = wn * 64 + nt * 16 + lr;   // local 0..127
#pragma unroll
                for (int r = 0; r < 4; ++r) {
                    const int row = row0 + wm * 64 + mt * 16 + lq * 4 + r;
                    C[(size_t)row * 128 + col] = __float2bfloat16(acc[mt][nt][r]);
                }
            }
    } else {
        bf16* Vt = Vtg + (size_t)zbl * (128 * 1024);
#pragma unroll
        for (int mt = 0; mt < 4; ++mt)
#pragma unroll
            for (int nt = 0; nt < 4; ++nt) {
                const int d = wn * 64 + nt * 16 + lr;
                const int rowb = row0 + wm * 64 + mt * 16 + lq * 4;
                union { bf16 h[4]; uint2 u; } pk;
#pragma unroll
                for (int r = 0; r < 4; ++r)
                    pk.h[r] = __float2bfloat16(acc[mt][nt][r]);
                *(uint2*)(Vt + (size_t)d * 1024 + rowb) = pk.u;
            }
    }
}

// ---------------------------------------------------------------------------
// Flash attention bf16 MFMA, Q in registers. grid (GQ heads, 16 q-tiles).
// BQ=64 (wave: 16 rows), BKV=64. LDS: Ks 16K + Vs 16K + Ps 8K = 40 KB.
// Ps is wave-private -> 2 barriers per kv-tile.
// ---------------------------------------------------------------------------
__global__ __launch_bounds__(256) void flash_bf16_kernel(
    const bf16* __restrict__ Qg,
    const bf16* __restrict__ Kg,
    const bf16* __restrict__ Vtg,
    float* __restrict__ z,
    const int* __restrict__ phase_p,
    int go)
{
    __shared__ bf16 Ks[64 * 128];
    __shared__ bf16 Vs[128 * 64];
    __shared__ bf16 Ps[64 * 64];

    const int ph  = phase_p[0] & 3;
    const int zbl = blockIdx.x;
    const int zb  = go + zbl;
    const int b   = zb / 12;
    const int hh  = zb % 12;
    const int n   = hh / 3;
    const int ks  = hh % 3;
    const int slot = (ks == 0) ? 0 : (ks == 1 ? 1 + (ph & 1) : 3 + (ph & 3));
    const int q0  = blockIdx.y * 64;

    const bf16* Qp = Qg  + (size_t)zbl * (1024 * 128);
    const bf16* Kp = Kg  + (size_t)zbl * (1024 * 128);
    const bf16* Vp = Vtg + (size_t)zbl * (128 * 1024);

    const int tid  = threadIdx.x;
    const int wave = tid >> 6;
    const int lane = tid & 63;
    const int lr = lane & 15;
    const int lq = lane >> 4;
    const int sr4 = lane >> 4, sc4 = (lane & 15) * 8;
    const int sr8 = lane >> 3, sc8 = (lane & 7) * 8;

    short8 qreg[4];
#pragma unroll
    for (int s = 0; s < 4; ++s)
        qreg[s] = *(const short8*)(Qp + (size_t)(q0 + wave * 16 + lr) * 128
                                   + s * 32 + lq * 8);

    f32x4 accO[8];
    float m_i[4], l_i[4];
#pragma unroll
    for (int j = 0; j < 8; ++j) accO[j] = (f32x4){0.f, 0.f, 0.f, 0.f};
#pragma unroll
    for (int r = 0; r < 4; ++r) { m_i[r] = -1e30f; l_i[r] = 0.f; }
    const float sc = 0.08838834764831845f;   // 1/sqrt(128)

    for (int j0 = 0; j0 <= q0; j0 += 64) {
#pragma unroll
        for (int j = 0; j < 4; ++j) {
            const int rg = wave * 16 + j * 4;
            __builtin_amdgcn_global_load_lds(
                (const __attribute__((address_space(1))) unsigned int*)
                    (Kp + (size_t)(j0 + rg + sr4) * 128 + sc4),
                (__attribute__((address_space(3))) unsigned int*)(Ks + rg * 128),
                16, 0, 0);
        }
#pragma unroll
        for (int j = 0; j < 4; ++j) {
            const int rg = wave * 32 + j * 8;
            __builtin_amdgcn_global_load_lds(
                (const __attribute__((address_space(1))) unsigned int*)
                    (Vp + (size_t)(rg + sr8) * 1024 + j0 + sc8),
                (__attribute__((address_space(3))) unsigned int*)(Vs + rg * 64),
                16, 0, 0);
        }
        __syncthreads();

        f32x4 accS[4];
#pragma unroll
        for (int nt = 0; nt < 4; ++nt) accS[nt] = (f32x4){0.f, 0.f, 0.f, 0.f};
#pragma unroll
        for (int s = 0; s < 4; ++s) {
            short8 bk[4];
#pragma unroll
            for (int nt = 0; nt < 4; ++nt)
                bk[nt] = *(const short8*)&Ks[(nt * 16 + lr) * 128 + s * 32 + lq * 8];
#pragma unroll
            for (int nt = 0; nt < 4; ++nt)
                accS[nt] = __builtin_amdgcn_mfma_f32_16x16x32_bf16(
                    qreg[s], bk[nt], accS[nt], 0, 0, 0);
        }

        const bool need_mask = (j0 == q0);
#pragma unroll
        for (int r = 0; r < 4; ++r) {
            const int row = q0 + wave * 16 + lq * 4 + r;
            float sv[4];
#pragma unroll
            for (int nt = 0; nt < 4; ++nt) {
                float v = accS[nt][r] * sc;
                if (need_mask && (j0 + nt * 16 + lr > row)) v = -1e30f;
                sv[nt] = v;
            }
            float mx = fmaxf(fmaxf(sv[0], sv[1]), fmaxf(sv[2], sv[3]));
#pragma unroll
            for (int msk = 8; msk; msk >>= 1) mx = fmaxf(mx, __shfl_xor(mx, msk, 16));
            float mnew = fmaxf(m_i[r], mx);
            float al   = __expf(m_i[r] - mnew);
            float rs = 0.f;
#pragma unroll
            for (int nt = 0; nt < 4; ++nt) {
                sv[nt] = __expf(sv[nt] - mnew);
                rs += sv[nt];
            }
#pragma unroll
            for (int msk = 8; msk; msk >>= 1) rs += __shfl_xor(rs, msk, 16);
            l_i[r] = l_i[r] * al + rs;
            m_i[r] = mnew;
#pragma unroll
            for (int d8 = 0; d8 < 8; ++d8) accO[d8][r] *= al;
            const int prow = wave * 16 + lq * 4 + r;
#pragma unroll
            for (int nt = 0; nt < 4; ++nt)
                Ps[prow * 64 + nt * 16 + lr] = __float2bfloat16(sv[nt]);
        }
        // Ps is wave-private: no barrier needed before PV

#pragma unroll
        for (int kvs = 0; kvs < 64; kvs += 32) {
            short8 ap = *(const short8*)&Ps[(wave * 16 + lr) * 64 + kvs + lq * 8];
            short8 bv[8];
#pragma unroll
            for (int d8 = 0; d8 < 8; ++d8)
                bv[d8] = *(const short8*)&Vs[(d8 * 16 + lr) * 64 + kvs + lq * 8];
#pragma unroll
            for (int d8 = 0; d8 < 8; ++d8)
                accO[d8] = __builtin_amdgcn_mfma_f32_16x16x32_bf16(
                    ap, bv[d8], accO[d8], 0, 0, 0);
        }
        __syncthreads();
    }

#pragma unroll
    for (int r = 0; r < 4; ++r) {
        const int t = q0 + wave * 16 + lq * 4 + r;
        const float inv = 1.0f / l_i[r];
        float* dst = z + (size_t)(b * 1024 + t) * ND + n * DD + slot * DH;
#pragma unroll
        for (int d8 = 0; d8 < 8; ++d8)
            dst[d8 * 16 + lr] += accO[d8][r] * inv;
    }
}

// ---------------------------------------------------------------------------
// fp32 -> bf16 elementwise (n4 = n/4)
// ---------------------------------------------------------------------------
__global__ __launch_bounds__(256) void cvt_bf16_kernel(const float* __restrict__ src,
                                                       bf16* __restrict__ dst,
                                                       int n4)
{
    int i = blockIdx.x * 256 + threadIdx.x;
    if (i < n4) {
        float4 v = ((const float4*)src)[i];
        bf16* d = dst + (size_t)i * 4;
        d[0] = __float2bfloat16(v.x);
        d[1] = __float2bfloat16(v.y);
        d[2] = __float2bfloat16(v.z);
        d[3] = __float2bfloat16(v.w);
    }
}

// Wqkv (12,128,384) fp32 -> Wt (12,384,128) bf16
__global__ __launch_bounds__(256) void cvt_wqkv_kernel(const float* __restrict__ W,
                                                       bf16* __restrict__ Wt)
{
    int o = blockIdx.x * 256 + threadIdx.x;
    if (o < 12 * 384 * 128) {
        int i = o / 49152, rem = o % 49152;
        int e = rem / 128, d = rem % 128;
        Wt[o] = __float2bfloat16(W[(size_t)i * 49152 + d * 384 + e]);
    }
}

// ---------------------------------------------------------------------------
// Attention-input LayerNorm -> bf16 head-major xh. grid = GQ*256 blocks.
// ---------------------------------------------------------------------------
__global__ __launch_bounds__(256) void ln_attn_kernel(const float* __restrict__ z,
                                                      bf16* __restrict__ xh,
                                                      const float* __restrict__ scale,
                                                      const float* __restrict__ bias,
                                                      const int* __restrict__ phase_p,
                                                      int bt0)
{
    const int ph   = phase_p[0] & 3;
    const int lane = threadIdx.x & 63;
    const int row  = blockIdx.x * 4 + (threadIdx.x >> 6);
    const int k    = row % 3;
    const int n    = (row / 3) & 3;
    const int btl  = row / 12;
    const int slot = (k == 0) ? 0 : (k == 1 ? 1 + (ph & 1) : 3 + (ph & 3));
    const int bt   = bt0 + btl;

    const float* src = z + (size_t)bt * ND + n * DD + slot * DH + lane * 2;
    float2 v = *(const float2*)src;
    float s = v.x + v.y;
    float q = v.x * v.x + v.y * v.y;
#pragma unroll
    for (int m = 32; m; m >>= 1) { s += __shfl_xor(s, m); q += __shfl_xor(q, m); }
    float mu  = s * (1.0f / 128.0f);
    float var = q * (1.0f / 128.0f) - mu * mu;
    float r   = rsqrtf(var + 1e-5f);

    float2 sc2 = *(const float2*)(scale + lane * 2);
    float2 bi2 = *(const float2*)(bias + lane * 2);
    const int bl = btl >> 10, t = btl & 1023;
    union { bf16 h[2]; unsigned int u; } pk;
    pk.h[0] = __float2bfloat16((v.x - mu) * r * sc2.x + bi2.x);
    pk.h[1] = __float2bfloat16((v.y - mu) * r * sc2.y + bi2.y);
    *(unsigned int*)(xh + (size_t)((bl * 12 + n * 3 + k) * 1024 + t) * DH + lane * 2) = pk.u;
}

// ---------------------------------------------------------------------------
// Row LayerNorm fp32 out (W=3584 decoder), safe in-place.
// ---------------------------------------------------------------------------
template<int W>
__global__ __launch_bounds__(256) void ln_row_kernel(const float* __restrict__ in,
                                                     float* __restrict__ outp,
                                                     const float* __restrict__ scale,
                                                     const float* __restrict__ bias)
{
    constexpr int NIT = (W + 255) / 256;
    const int row = blockIdx.x;
    const int tid = threadIdx.x;
    const float* rp = in + (size_t)row * W;

    float v[NIT];
    float s = 0.f, q = 0.f;
#pragma unroll
    for (int i = 0; i < NIT; ++i) {
        int idx = tid + i * 256;
        if (idx < W) { float t = rp[idx]; v[i] = t; s += t; q += t * t; }
        else v[i] = 0.f;
    }
#pragma unroll
    for (int m = 32; m; m >>= 1) { s += __shfl_xor(s, m); q += __shfl_xor(q, m); }
    __shared__ float ss[4], sq[4];
    if ((tid & 63) == 0) { ss[tid >> 6] = s; sq[tid >> 6] = q; }
    __syncthreads();
    s = ss[0] + ss[1] + ss[2] + ss[3];
    q = sq[0] + sq[1] + sq[2] + sq[3];
    float mu  = s * (1.0f / W);
    float var = q * (1.0f / W) - mu * mu;
    float r   = rsqrtf(var + 1e-5f);

    float* op = outp + (size_t)row * W;
#pragma unroll
    for (int i = 0; i < NIT; ++i) {
        int idx = tid + i * 256;
        if (idx < W) op[idx] = (v[i] - mu) * r * scale[idx] + bias[idx];
    }
}

// ---------------------------------------------------------------------------
// Row LayerNorm, W=896, bf16 output (mixer input).
// ---------------------------------------------------------------------------
__global__ __launch_bounds__(256) void ln_row_bf16_kernel(const float* __restrict__ in,
                                                          bf16* __restrict__ outp,
                                                          const float* __restrict__ scale,
                                                          const float* __restrict__ bias)
{
    constexpr int W = 896, NIT = 4;
    const int row = blockIdx.x;
    const int tid = threadIdx.x;
    const float* rp = in + (size_t)row * W;

    float v[NIT];
    float s = 0.f, q = 0.f;
#pragma unroll
    for (int i = 0; i < NIT; ++i) {
        int idx = tid + i * 256;
        if (idx < W) { float t = rp[idx]; v[i] = t; s += t; q += t * t; }
        else v[i] = 0.f;
    }
#pragma unroll
    for (int m = 32; m; m >>= 1) { s += __shfl_xor(s, m); q += __shfl_xor(q, m); }
    __shared__ float ss[4], sq[4];
    if ((tid & 63) == 0) { ss[tid >> 6] = s; sq[tid >> 6] = q; }
    __syncthreads();
    s = ss[0] + ss[1] + ss[2] + ss[3];
    q = sq[0] + sq[1] + sq[2] + sq[3];
    float mu  = s * (1.0f / W);
    float var = q * (1.0f / W) - mu * mu;
    float r   = rsqrtf(var + 1e-5f);

    bf16* op = outp + (size_t)row * W;
#pragma unroll
    for (int i = 0; i < NIT; ++i) {
        int idx = tid + i * 256;
        if (idx < W)
            op[idx] = __float2bfloat16((v[i] - mu) * r * scale[idx] + bias[idx]);
    }
}

// ---------------------------------------------------------------------------
// Launcher. ws-aware (ws>=205 MB proven by R6's CH=8192 run passing):
//   attn: GQ=96 (102 MB in R) if ws>=230 MB else GQ=48 (51.5 MB).
//   mixer: CH=8192 (86.2 MB) if ws>=205 MB else 4096 (49.5 MB).
// ---------------------------------------------------------------------------
extern "C" void kernel_launch(void* const* d_in, const int* in_sizes, int n_in,
                              void* d_out, int out_size, void* d_ws, size_t ws_size,
                              hipStream_t stream)
{
    const float* x          = (const float*)d_in[0];
    const float* enc_base_w = (const float*)d_in[1];
    const float* enc_A_w    = (const float*)d_in[2];
    const float* enc_B      = (const float*)d_in[3];
    const float* enc_beta   = (const float*)d_in[4];
    const float* Wqkv       = (const float*)d_in[5];
    const float* ln_attn_s  = (const float*)d_in[6];
    const float* ln_attn_b  = (const float*)d_in[7];
    const float* ln_mix_s   = (const float*)d_in[8];
    const float* ln_mix_b   = (const float*)d_in[9];
    const float* w1         = (const float*)d_in[10];
    const float* b1         = (const float*)d_in[11];
    const float* w2         = (const float*)d_in[12];
    const float* b2         = (const float*)d_in[13];
    const float* dec_ln_s   = (const float*)d_in[14];
    const float* dec_ln_b   = (const float*)d_in[15];
    const float* dec_down   = (const float*)d_in[16];
    const float* dec_up     = (const float*)d_in[17];
    const int*   phase_p    = (const int*)d_in[18];
    float* out = (float*)d_out;

    float* ws = (float*)d_ws;
    float* z  = ws;                                  // 8192*3584 fp32 (persistent)
    float* R  = ws + (size_t)BT * ND;

    const int GQ = (ws_size >= 230000000UL) ? 96 : 48;
    const int CH = (ws_size >= 205000000UL) ? 8192 : 4096;

    // encoder phase
    bf16* xb   = (bf16*)R;                           // 8192*1024
    bf16* Wenc = xb + (size_t)BT * IO;               // 3584*1024
    // attention phase
    bf16* Wt   = (bf16*)R;                           // 12*384*128
    bf16* xh_b = Wt + 12 * 384 * 128;                // GQ*1024*128
    bf16* Qb   = xh_b + (size_t)GQ * 1024 * 128;     // GQ*1024*128
    bf16* Kb   = Qb + (size_t)GQ * 1024 * 128;       // GQ*1024*128
    bf16* Vtg  = Kb + (size_t)GQ * 1024 * 128;       // GQ*128*1024
    // mixer phase
    bf16* w1b  = (bf16*)R;                           // 3584*896
    bf16* w2b  = w1b + (size_t)HID * DD;             // 896*3584
    bf16* hm   = w2b + (size_t)DD * HID;             // CH*896
    bf16* gbuf = hm + (size_t)CH * DD;               // CH*3584
    // dec phase
    float* t1  = R;                                  // 8192*64 fp32

    // --- Encoder: fold low-rank into W_enc, then one bf16 GEMM into z
    cvt_bf16_kernel<<<dim3(8192), 256, 0, stream>>>(x, xb, BT * IO / 4);
    pack_enc_kernel<<<dim3(16, 56), 256, 0, stream>>>(enc_base_w, enc_A_w, enc_B,
                                                      enc_beta, Wenc);
    gemm_bf16_kernel<0><<<dim3(28, 64), 256, 0, stream>>>(xb, Wenc, z, nullptr,
                                                          ND, IO, nullptr);

    // --- Attention (bf16 MFMA), GQ heads per group
    cvt_wqkv_kernel<<<dim3(2304), 256, 0, stream>>>(Wqkv, Wt);
    const int ngroups = 96 / GQ;
    for (int g = 0; g < ngroups; ++g) {
        ln_attn_kernel<<<dim3(GQ * 256), 256, 0, stream>>>(z, xh_b, ln_attn_s,
                                                           ln_attn_b, phase_p,
                                                           g * (GQ / 12) * 1024);
        qkv_bf16_kernel<<<dim3(3, 8, GQ), 256, 0, stream>>>(xh_b, Wt, Qb, Kb, Vtg,
                                                            phase_p, g * GQ);
        flash_bf16_kernel<<<dim3(GQ, 16), 256, 0, stream>>>(Qb, Kb, Vtg, z,
                                                            phase_p, g * GQ);
    }

    // --- Mixer MLP on bf16 MFMA, chunks of CH rows (of 32768 x 896)
    cvt_bf16_kernel<<<dim3(3136), 256, 0, stream>>>(w1, w1b, HID * DD / 4);
    cvt_bf16_kernel<<<dim3(3136), 256, 0, stream>>>(w2, w2b, DD * HID / 4);
    for (int c = 0; c < 32768 / CH; ++c) {
        float* zc = z + (size_t)c * CH * DD;
        ln_row_bf16_kernel<<<dim3(CH), 256, 0, stream>>>(zc, hm, ln_mix_s, ln_mix_b);
        gemm_bf16_kernel<1><<<dim3(28, CH / 128), 256, 0, stream>>>(
            hm, w1b, nullptr, gbuf, HID, DD, b1);
        gemm_bf16_kernel<2><<<dim3(7, CH / 128), 256, 0, stream>>>(
            gbuf, w2b, zc, nullptr, DD, HID, b2);
    }

    // --- Decoder: LN in place, split-K down-projection, up-projection
    ln_row_kernel<3584><<<dim3(8192), 256, 0, stream>>>(z, z, dec_ln_s, dec_ln_b);
    hipMemsetAsync(t1, 0, (size_t)BT * RK * sizeof(float), stream);
    gemm_splitk_kernel<8><<<dim3(1, 128, 8), 256, 0, stream>>>(z, dec_down, t1,
                                                               RK, ND);
    gemm_kernel<128, 128, 16, 8, 8>
        <<<dim3(8, 64), 256, 0, stream>>>(t1, dec_up, out, IO, RK);
}